// Round 1
// baseline (21806.573 us; speedup 1.0000x reference)
//
#include <hip/hip_runtime.h>
#include <hip/hip_bf16.h>

// ---------------- problem constants ----------------
#define NB 16
#define NH 36
#define NW 100
#define NC0 512
#define NC1 1024
#define NC2 128
#define NPOS (NB*NH*NW)        // 57600
#define K1 4608                // 9 taps * 512

__device__ __forceinline__ float bf2f(unsigned short u) {
  union { unsigned int i; float f; } c; c.i = ((unsigned int)u) << 16; return c.f;
}
// round-to-nearest-even f32 -> bf16 bits (finite inputs)
__device__ __forceinline__ unsigned short f2bf(float f) {
  union { float f; unsigned int i; } c; c.f = f;
  unsigned int x = c.i;
  x += 0x7fffu + ((x >> 16) & 1u);
  return (unsigned short)(x >> 16);
}

// ============================================================
// conv1: dilated 3x3 (dilation 4, pad 4), 512->1024, as GEMM
// M=57600 (b,h,w), K=4608 (tap*512+ci), N=1024. Output bf16.
// ============================================================
__global__ __launch_bounds__(256) void conv1_gemm(
    const float* __restrict__ in,    // (16,36,100,512)
    const float* __restrict__ w1,    // (4608,1024) row-major
    unsigned short* __restrict__ x1) // (57600,1024) bf16
{
  __shared__ float As[64][33];
  __shared__ float Bs[32][128];
  __shared__ int rb[64], rh[64], rw[64];
  const int tid = threadIdx.x;
  const int m0 = blockIdx.y * 64;
  const int n0 = blockIdx.x * 128;
  if (tid < 64) {
    int m = m0 + tid;
    rw[tid] = m % 100;
    rh[tid] = (m / 100) % 36;
    rb[tid] = m / 3600;
  }
  __syncthreads();
  const int tm = tid >> 4, tn = tid & 15;
  float acc[4][8];
  #pragma unroll
  for (int i = 0; i < 4; ++i)
    #pragma unroll
    for (int j = 0; j < 8; ++j) acc[i][j] = 0.f;

  for (int k0 = 0; k0 < K1; k0 += 32) {
    const int tap = k0 >> 9;          // 0..8, constant within chunk (32|512)
    const int ci0 = k0 & 511;
    const int dh = (tap / 3) * 4 - 4;
    const int dw = (tap % 3) * 4 - 4;
    // stage A: 64 rows x 32 k  (512 float4, 2 per thread)
    #pragma unroll
    for (int t = 0; t < 2; ++t) {
      int idx = tid + t * 256;
      int r = idx >> 3, q = idx & 7;
      int ih = rh[r] + dh, iw = rw[r] + dw;
      float4 v = make_float4(0.f, 0.f, 0.f, 0.f);
      if ((unsigned)ih < 36u && (unsigned)iw < 100u)
        v = *(const float4*)(in + ((((long)rb[r]) * 36 + ih) * 100 + iw) * 512 + ci0 + q * 4);
      As[r][q*4+0] = v.x; As[r][q*4+1] = v.y; As[r][q*4+2] = v.z; As[r][q*4+3] = v.w;
    }
    // stage B: 32 x 128 (1024 float4, 4 per thread)
    #pragma unroll
    for (int t = 0; t < 4; ++t) {
      int idx = tid + t * 256;
      int kk = idx >> 5, q = idx & 31;
      *(float4*)&Bs[kk][q*4] = *(const float4*)(w1 + (long)(k0 + kk) * 1024 + n0 + q * 4);
    }
    __syncthreads();
    const float* ar = &As[tm*4][0];
    const float* br = &Bs[0][tn*8];
    #pragma unroll 8
    for (int kk = 0; kk < 32; ++kk) {
      float a0 = ar[kk], a1 = ar[33+kk], a2 = ar[66+kk], a3 = ar[99+kk];
      float4 bA = *(const float4*)(br + kk*128);
      float4 bB = *(const float4*)(br + kk*128 + 4);
      float bv[8] = {bA.x,bA.y,bA.z,bA.w,bB.x,bB.y,bB.z,bB.w};
      #pragma unroll
      for (int j = 0; j < 8; ++j) {
        acc[0][j] = fmaf(a0, bv[j], acc[0][j]);
        acc[1][j] = fmaf(a1, bv[j], acc[1][j]);
        acc[2][j] = fmaf(a2, bv[j], acc[2][j]);
        acc[3][j] = fmaf(a3, bv[j], acc[3][j]);
      }
    }
    __syncthreads();
  }
  #pragma unroll
  for (int i = 0; i < 4; ++i) {
    unsigned short* dst = x1 + (long)(m0 + tm*4 + i) * 1024 + n0 + tn*8;
    unsigned int pk[4];
    #pragma unroll
    for (int jj = 0; jj < 4; ++jj)
      pk[jj] = (unsigned int)f2bf(acc[i][2*jj]) | ((unsigned int)f2bf(acc[i][2*jj+1]) << 16);
    *reinterpret_cast<uint4*>(dst) = make_uint4(pk[0], pk[1], pk[2], pk[3]);
  }
}

// ---------------- per-channel stats over x1 (bf16) ----------------
__global__ __launch_bounds__(256) void stats1(const unsigned short* __restrict__ x1,
                                              float* __restrict__ sum, float* __restrict__ ssq)
{
  const int tid = threadIdx.x;
  const int c0 = tid * 4;
  float s0=0,s1=0,s2=0,s3=0,q0=0,q1=0,q2=0,q3=0;
  for (int r = blockIdx.x; r < NPOS; r += gridDim.x) {
    uint2 v = *(const uint2*)(x1 + (long)r * 1024 + c0);
    float f0 = bf2f(v.x & 0xffffu), f1 = bf2f(v.x >> 16);
    float f2 = bf2f(v.y & 0xffffu), f3 = bf2f(v.y >> 16);
    s0 += f0; q0 += f0*f0;  s1 += f1; q1 += f1*f1;
    s2 += f2; q2 += f2*f2;  s3 += f3; q3 += f3*f3;
  }
  atomicAdd(&sum[c0+0], s0); atomicAdd(&ssq[c0+0], q0);
  atomicAdd(&sum[c0+1], s1); atomicAdd(&ssq[c0+1], q1);
  atomicAdd(&sum[c0+2], s2); atomicAdd(&ssq[c0+2], q2);
  atomicAdd(&sum[c0+3], s3); atomicAdd(&ssq[c0+3], q3);
}

__global__ void finalize_bn(const float* __restrict__ sum, const float* __restrict__ ssq,
                            const float* __restrict__ scale, const float* __restrict__ bias,
                            float* __restrict__ ab, int C, float invN)
{
  int c = blockIdx.x * blockDim.x + threadIdx.x;
  if (c >= C) return;
  float mean = sum[c] * invN;
  float var  = ssq[c] * invN - mean * mean;
  float a = scale[c] * rsqrtf(var + 1e-5f);
  ab[c] = a;
  ab[C + c] = bias[c] - mean * a;
}

// ============================================================
// conv2: 1x1 1024->128 with fused bn1+relu on A. Output fp32.
// ============================================================
__global__ __launch_bounds__(256) void conv2_gemm(
    const unsigned short* __restrict__ x1, // (57600,1024) bf16
    const float* __restrict__ w2,          // (1024,128)
    const float* __restrict__ ab1,         // a[1024], b[1024]
    float* __restrict__ x2)                // (57600,128)
{
  __shared__ float As[64][33];
  __shared__ float Bs[32][128];
  __shared__ float sa[1024], sb[1024];
  const int tid = threadIdx.x;
  const int m0 = blockIdx.x * 64;
  for (int i = tid; i < 1024; i += 256) { sa[i] = ab1[i]; sb[i] = ab1[1024 + i]; }
  __syncthreads();
  const int tm = tid >> 4, tn = tid & 15;
  float acc[4][8];
  #pragma unroll
  for (int i = 0; i < 4; ++i)
    #pragma unroll
    for (int j = 0; j < 8; ++j) acc[i][j] = 0.f;

  for (int k0 = 0; k0 < 1024; k0 += 32) {
    { // stage A: 64 rows x 32 bf16, apply relu(a*x+b); 8 bf16 per thread
      int r = tid >> 2, q = tid & 3;
      uint4 v = *(const uint4*)(x1 + (long)(m0 + r) * 1024 + k0 + q * 8);
      unsigned int w[4] = {v.x, v.y, v.z, v.w};
      #pragma unroll
      for (int jj = 0; jj < 4; ++jj) {
        int k = k0 + q*8 + jj*2;
        float flo = bf2f((unsigned short)(w[jj] & 0xffffu));
        float fhi = bf2f((unsigned short)(w[jj] >> 16));
        As[r][q*8 + jj*2 + 0] = fmaxf(fmaf(flo, sa[k],   sb[k]),   0.f);
        As[r][q*8 + jj*2 + 1] = fmaxf(fmaf(fhi, sa[k+1], sb[k+1]), 0.f);
      }
    }
    #pragma unroll
    for (int t = 0; t < 4; ++t) {
      int idx = tid + t * 256;
      int kk = idx >> 5, q = idx & 31;
      *(float4*)&Bs[kk][q*4] = *(const float4*)(w2 + (long)(k0 + kk) * 128 + q * 4);
    }
    __syncthreads();
    const float* ar = &As[tm*4][0];
    const float* br = &Bs[0][tn*8];
    #pragma unroll 8
    for (int kk = 0; kk < 32; ++kk) {
      float a0 = ar[kk], a1 = ar[33+kk], a2 = ar[66+kk], a3 = ar[99+kk];
      float4 bA = *(const float4*)(br + kk*128);
      float4 bB = *(const float4*)(br + kk*128 + 4);
      float bv[8] = {bA.x,bA.y,bA.z,bA.w,bB.x,bB.y,bB.z,bB.w};
      #pragma unroll
      for (int j = 0; j < 8; ++j) {
        acc[0][j] = fmaf(a0, bv[j], acc[0][j]);
        acc[1][j] = fmaf(a1, bv[j], acc[1][j]);
        acc[2][j] = fmaf(a2, bv[j], acc[2][j]);
        acc[3][j] = fmaf(a3, bv[j], acc[3][j]);
      }
    }
    __syncthreads();
  }
  #pragma unroll
  for (int i = 0; i < 4; ++i) {
    float* dst = x2 + (long)(m0 + tm*4 + i) * 128 + tn*8;
    *(float4*)dst       = make_float4(acc[i][0], acc[i][1], acc[i][2], acc[i][3]);
    *(float4*)(dst + 4) = make_float4(acc[i][4], acc[i][5], acc[i][6], acc[i][7]);
  }
}

// ---------------- stats over x2 (fp32, 128 ch) ----------------
__global__ __launch_bounds__(256) void stats2(const float* __restrict__ x2,
                                              float* __restrict__ sum, float* __restrict__ ssq)
{
  const int c = threadIdx.x & 127;
  const int g = threadIdx.x >> 7;
  float s = 0.f, q = 0.f;
  for (int r = blockIdx.x * 2 + g; r < NPOS; r += gridDim.x * 2) {
    float v = x2[(long)r * 128 + c];
    s += v; q += v * v;
  }
  atomicAdd(&sum[c], s); atomicAdd(&ssq[c], q);
}

// ---------------- apply bn2 + relu in place ----------------
__global__ __launch_bounds__(256) void apply_bn(float* __restrict__ x, const float* __restrict__ ab)
{
  int idx = (blockIdx.x * 256 + threadIdx.x) * 4;
  if (idx >= NPOS * 128) return;
  int c = idx & 127;
  float4 v = *(float4*)(x + idx);
  v.x = fmaxf(fmaf(v.x, ab[c+0], ab[128+c+0]), 0.f);
  v.y = fmaxf(fmaf(v.y, ab[c+1], ab[128+c+1]), 0.f);
  v.z = fmaxf(fmaf(v.z, ab[c+2], ab[128+c+2]), 0.f);
  v.w = fmaxf(fmaf(v.w, ab[c+3], ab[128+c+3]), 0.f);
  *(float4*)(x + idx) = v;
}

// ============================================================
// message-passing step: x[out + b*BS + p*sP + c] += relu(
//   sum_{k,ci} x[in + b*BS + (p+k-4)*sP + ci] * W[k,ci,c] )
// L = conv length; one launch per recurrence step.
// ============================================================
__global__ __launch_bounds__(256) void mp_step(
    float* __restrict__ x, const float* __restrict__ W,
    int in_off, int out_off, int L, int strideP)
{
  __shared__ float lds[16 * 128];   // rows p0-4 .. p0+11
  const int b = blockIdx.y;
  const int p0 = blockIdx.x * 8;
  const int tid = threadIdx.x;
  const int co = tid & 127;
  const int pg = tid >> 7;          // 0..1, 4 p each
  const float* inb = x + in_off + b * 460800;
  #pragma unroll
  for (int t = 0; t < 2; ++t) {
    int idx = tid + t * 256;
    int r = idx >> 5, q = idx & 31;
    int p = p0 - 4 + r;
    float4 v = make_float4(0.f, 0.f, 0.f, 0.f);
    if ((unsigned)p < (unsigned)L)
      v = *(const float4*)(inb + (long)p * strideP + q * 4);
    *(float4*)&lds[r * 128 + q * 4] = v;
  }
  __syncthreads();
  float a0=0.f, a1=0.f, a2=0.f, a3=0.f;
  const float* wbase = W + co;
  #pragma unroll
  for (int k = 0; k < 9; ++k) {
    const float* lrow = &lds[(pg*4 + k) * 128];
    const float* wk = wbase + k * 16384;
    #pragma unroll 4
    for (int ci = 0; ci < 128; ++ci) {
      float wv = wk[ci * 128];
      a0 = fmaf(lrow[ci      ], wv, a0);
      a1 = fmaf(lrow[ci + 128], wv, a1);
      a2 = fmaf(lrow[ci + 256], wv, a2);
      a3 = fmaf(lrow[ci + 384], wv, a3);
    }
  }
  float* outb = x + out_off + b * 460800;
  int pb = p0 + pg * 4;
  if (pb + 0 < L) outb[(long)(pb+0) * strideP + co] += fmaxf(a0, 0.f);
  if (pb + 1 < L) outb[(long)(pb+1) * strideP + co] += fmaxf(a1, 0.f);
  if (pb + 2 < L) outb[(long)(pb+2) * strideP + co] += fmaxf(a2, 0.f);
  if (pb + 3 < L) outb[(long)(pb+3) * strideP + co] += fmaxf(a3, 0.f);
}

// ---------------- segmentation head: 128 -> 5 + bias ----------------
__global__ __launch_bounds__(256) void seg_head(
    const float* __restrict__ xn, const float* __restrict__ w_seg,
    const float* __restrict__ b_seg, float* __restrict__ logits)
{
  __shared__ float ws[128 * 5];
  __shared__ float xs[32][129];
  const int tid = threadIdx.x;
  for (int i = tid; i < 640; i += 256) ws[i] = w_seg[i];
  const int pos0 = blockIdx.x * 32;
  for (int idx = tid; idx < 32 * 32; idx += 256) {
    int r = idx >> 5, q = idx & 31;
    float4 v = *(const float4*)(xn + (long)(pos0 + r) * 128 + q * 4);
    xs[r][q*4+0]=v.x; xs[r][q*4+1]=v.y; xs[r][q*4+2]=v.z; xs[r][q*4+3]=v.w;
  }
  __syncthreads();
  int r = tid >> 3, f = tid & 7;
  if (f < 5) {
    float acc = b_seg[f];
    #pragma unroll 4
    for (int ci = 0; ci < 128; ++ci) acc = fmaf(xs[r][ci], ws[ci*5 + f], acc);
    logits[(long)(pos0 + r) * 5 + f] = acc;
  }
}

// ---------------- softmax + 2x2 mean pool -> p (16,4500) ----------------
__global__ __launch_bounds__(256) void softpool(const float* __restrict__ logits, float* __restrict__ p)
{
  int idx = blockIdx.x * 256 + threadIdx.x;
  if (idx >= 16 * 18 * 50) return;
  int ww = idx % 50, hh = (idx / 50) % 18, b = idx / 900;
  float avg[5] = {0,0,0,0,0};
  #pragma unroll
  for (int i = 0; i < 2; ++i)
    #pragma unroll
    for (int j = 0; j < 2; ++j) {
      const float* L = logits + ((long)((b*36 + hh*2 + i) * 100) + ww*2 + j) * 5;
      float l0=L[0], l1=L[1], l2=L[2], l3=L[3], l4=L[4];
      float m = fmaxf(fmaxf(fmaxf(l0,l1), fmaxf(l2,l3)), l4);
      float e0=expf(l0-m), e1=expf(l1-m), e2=expf(l2-m), e3=expf(l3-m), e4=expf(l4-m);
      float inv = 1.f / (e0+e1+e2+e3+e4);
      avg[0] += e0*inv; avg[1] += e1*inv; avg[2] += e2*inv; avg[3] += e3*inv; avg[4] += e4*inv;
    }
  float* dst = p + (long)b * 4500 + (hh * 50 + ww) * 5;
  #pragma unroll
  for (int f = 0; f < 5; ++f) dst[f] = avg[f] * 0.25f;
}

// ---------------- fc1: (16,4500)@(4500,128)+b, relu ----------------
__global__ __launch_bounds__(128) void fc1_kernel(
    const float* __restrict__ p, const float* __restrict__ w,
    const float* __restrict__ bias, float* __restrict__ z)
{
  __shared__ float ps[4500];
  const int b = blockIdx.x, tid = threadIdx.x;
  for (int i = tid; i < 4500; i += 128) ps[i] = p[(long)b * 4500 + i];
  __syncthreads();
  float acc = bias[tid];
  #pragma unroll 4
  for (int m = 0; m < 4500; ++m) acc = fmaf(ps[m], w[(long)m * 128 + tid], acc);
  z[b * 128 + tid] = fmaxf(acc, 0.f);
}

// ---------------- fc2: (16,128)@(128,4)+b ----------------
__global__ void fc2_kernel(const float* __restrict__ z, const float* __restrict__ w,
                           const float* __restrict__ bias, float* __restrict__ out)
{
  int t = threadIdx.x;
  if (t >= 64) return;
  int b = t >> 2, j = t & 3;
  float acc = bias[j];
  #pragma unroll 4
  for (int n = 0; n < 128; ++n) acc = fmaf(z[b*128 + n], w[n*4 + j], acc);
  out[b*4 + j] = acc;
}

// ---------------- 8x bilinear resize (half-pixel, edge-clamped) ----------------
__global__ __launch_bounds__(256) void resize_bilinear(
    const float* __restrict__ logits, float* __restrict__ out)
{
  int idx = blockIdx.x * 256 + threadIdx.x;
  if (idx >= 18432000) return;
  int f = idx % 5;
  int t = idx / 5;
  int ow = t % 800; t /= 800;
  int oh = t % 288;
  int b = t / 288;
  float sh = (oh + 0.5f) * 0.125f - 0.5f;
  float sw = (ow + 0.5f) * 0.125f - 0.5f;
  int h0 = (int)floorf(sh); float fh = sh - (float)h0;
  int w0 = (int)floorf(sw); float fw = sw - (float)w0;
  int h1 = min(h0 + 1, 35); h0 = max(h0, 0);
  int w1 = min(w0 + 1, 99); w0 = max(w0, 0);
  const float* Lb = logits + (long)b * 36 * 100 * 5 + f;
  float v00 = Lb[(h0*100 + w0)*5], v01 = Lb[(h0*100 + w1)*5];
  float v10 = Lb[(h1*100 + w0)*5], v11 = Lb[(h1*100 + w1)*5];
  float v = (1.f-fh) * ((1.f-fw)*v00 + fw*v01) + fh * ((1.f-fw)*v10 + fw*v11);
  out[idx] = v;
}

// ============================================================
extern "C" void kernel_launch(void* const* d_in, const int* in_sizes, int n_in,
                              void* d_out, int out_size, void* d_ws, size_t ws_size,
                              hipStream_t stream)
{
  (void)in_sizes; (void)n_in; (void)out_size; (void)ws_size;
  const float* features = (const float*)d_in[0];
  const float* w_conv1  = (const float*)d_in[1];
  const float* bn1_s    = (const float*)d_in[2];
  const float* bn1_b    = (const float*)d_in[3];
  const float* w_conv2  = (const float*)d_in[4];
  const float* bn2_s    = (const float*)d_in[5];
  const float* bn2_b    = (const float*)d_in[6];
  const float* w_vf     = (const float*)d_in[7];
  const float* w_vr     = (const float*)d_in[8];
  const float* w_hf     = (const float*)d_in[9];
  const float* w_hr     = (const float*)d_in[10];
  const float* w_seg    = (const float*)d_in[11];
  const float* b_seg    = (const float*)d_in[12];
  const float* w_fc1    = (const float*)d_in[13];
  const float* b_fc1    = (const float*)d_in[14];
  const float* w_fc2    = (const float*)d_in[15];
  const float* b_fc2    = (const float*)d_in[16];

  char* ws = (char*)d_ws;
  unsigned short* x1 = (unsigned short*)ws;          // 57600*1024 bf16 = 117,964,800 B
  float* x2     = (float*)(ws + 117964800);          // 57600*128 f32  =  29,491,200 B
  float* logits = (float*)(ws + 147456000);          // 57600*5   f32  =   1,152,000 B
  float* pbuf   = (float*)(ws + 148608000);          // 16*4500        =     288,000 B
  float* zbuf   = (float*)(ws + 148896000);          // 16*128         =       8,192 B
  float* stats  = (float*)(ws + 148904192);          // 2304 floats    =       9,216 B
  float* ab1    = (float*)(ws + 148913408);          // 2048 floats
  float* ab2    = (float*)(ws + 148921600);          // 256 floats
  float* outf   = (float*)d_out;

  hipMemsetAsync(stats, 0, 2304 * sizeof(float), stream);

  conv1_gemm<<<dim3(8, 900), 256, 0, stream>>>(features, w_conv1, x1);
  stats1<<<512, 256, 0, stream>>>(x1, stats, stats + 1024);
  finalize_bn<<<4, 256, 0, stream>>>(stats, stats + 1024, bn1_s, bn1_b, ab1, 1024, 1.0f/57600.0f);
  conv2_gemm<<<900, 256, 0, stream>>>(x1, w_conv2, ab1, x2);
  stats2<<<256, 256, 0, stream>>>(x2, stats + 2048, stats + 2176);
  finalize_bn<<<1, 128, 0, stream>>>(stats + 2048, stats + 2176, bn2_s, bn2_b, ab2, 128, 1.0f/57600.0f);
  apply_bn<<<7200, 256, 0, stream>>>(x2, ab2);

  // message passing: strictly sequential recurrence, one launch per step
  for (int i = 1; i < 36; ++i)     // vertical forward: row i += relu(conv_w(row i-1))
    mp_step<<<dim3(13, NB), 256, 0, stream>>>(x2, w_vf, (i-1)*12800, i*12800, 100, 128);
  for (int i = 34; i >= 0; --i)    // vertical reverse
    mp_step<<<dim3(13, NB), 256, 0, stream>>>(x2, w_vr, (i+1)*12800, i*12800, 100, 128);
  for (int j = 1; j < 100; ++j)    // horizontal forward: col j += relu(conv_h(col j-1))
    mp_step<<<dim3(5, NB), 256, 0, stream>>>(x2, w_hf, (j-1)*128, j*128, 36, 12800);
  for (int j = 98; j >= 0; --j)    // horizontal reverse
    mp_step<<<dim3(5, NB), 256, 0, stream>>>(x2, w_hr, (j+1)*128, j*128, 36, 12800);

  seg_head<<<1800, 256, 0, stream>>>(x2, w_seg, b_seg, logits);
  softpool<<<57, 256, 0, stream>>>(logits, pbuf);
  fc1_kernel<<<16, 128, 0, stream>>>(pbuf, w_fc1, b_fc1, zbuf);
  fc2_kernel<<<1, 64, 0, stream>>>(zbuf, w_fc2, b_fc2, outf + 18432000);
  resize_bilinear<<<72000, 256, 0, stream>>>(logits, outf);
}

// Round 2
// 14137.216 us; speedup vs baseline: 1.5425x; 1.5425x over previous
//
#include <hip/hip_runtime.h>
#include <hip/hip_bf16.h>

#define NB 16
#define NPOS 57600

typedef short bf16x8 __attribute__((ext_vector_type(8)));
typedef float f32x4 __attribute__((ext_vector_type(4)));

__device__ __forceinline__ float bf2f(unsigned short u) {
  union { unsigned int i; float f; } c; c.i = ((unsigned int)u) << 16; return c.f;
}
// round-to-nearest-even f32 -> bf16 bits
__device__ __forceinline__ unsigned short f2bf(float f) {
  union { float f; unsigned int i; } c; c.f = f;
  unsigned int x = c.i;
  x += 0x7fffu + ((x >> 16) & 1u);
  return (unsigned short)(x >> 16);
}
__device__ __forceinline__ unsigned int pk2(float lo, float hi) {
  return (unsigned int)f2bf(lo) | ((unsigned int)f2bf(hi) << 16);
}

__device__ __forceinline__ void gload_lds16(const void* g, void* l) {
  __builtin_amdgcn_global_load_lds(
      (const __attribute__((address_space(1))) unsigned int*)(g),
      (__attribute__((address_space(3))) unsigned int*)(l), 16, 0, 0);
}

// ---------------- weight conversions (one-time, tiny) ----------------
// w1 (4608,1024) f32 -> w1t (1024,4608) bf16
__global__ __launch_bounds__(256) void convert_w1t(const float* __restrict__ w,
                                                   unsigned short* __restrict__ wt)
{
  int idx = blockIdx.x * 256 + threadIdx.x;     // 589824 jobs
  int n = idx & 1023;
  int k0 = (idx >> 10) * 8;
  unsigned int o[4];
#pragma unroll
  for (int j = 0; j < 4; ++j) {
    float lo = w[(long)(k0 + 2*j)     * 1024 + n];
    float hi = w[(long)(k0 + 2*j + 1) * 1024 + n];
    o[j] = pk2(lo, hi);
  }
  *(uint4*)(wt + (long)n * 4608 + k0) = make_uint4(o[0], o[1], o[2], o[3]);
}

// w2 (1024,128) f32 -> w2t (128,1024) bf16
__global__ __launch_bounds__(256) void convert_w2t(const float* __restrict__ w,
                                                   unsigned short* __restrict__ wt)
{
  int idx = blockIdx.x * 256 + threadIdx.x;     // 16384 jobs
  int n = idx & 127;
  int k0 = (idx >> 7) * 8;
  unsigned int o[4];
#pragma unroll
  for (int j = 0; j < 4; ++j) {
    float lo = w[(long)(k0 + 2*j)     * 128 + n];
    float hi = w[(long)(k0 + 2*j + 1) * 128 + n];
    o[j] = pk2(lo, hi);
  }
  *(uint4*)(wt + (long)n * 1024 + k0) = make_uint4(o[0], o[1], o[2], o[3]);
}

// ============================================================
// conv1 via MFMA: implicit-im2col GEMM M=57600, K=4608, N=1024
// A reg-staged (f32->bf16 cvt + OOB zeros), B via global_load_lds.
// 128x128 tile, BK=32, 4 waves (2x2), m97 2-barrier structure.
// ============================================================
__global__ __launch_bounds__(256) void conv1_mfma(
    const float* __restrict__ in,            // (16,36,100,512) f32
    const unsigned short* __restrict__ w1t,  // (1024,4608) bf16 [n][k]
    unsigned short* __restrict__ x1)         // (57600,1024) bf16
{
  __shared__ unsigned short Al[128 * 32];
  __shared__ unsigned short Bl[128 * 32];
  const int tid  = threadIdx.x;
  const int lane = tid & 63;
  const int wave = tid >> 6;
  const int wm = wave >> 1, wn = wave & 1;
  const int m0 = blockIdx.y * 128;
  const int n0 = blockIdx.x * 128;

  int arow[2], akl[2], ab_[2], ah_[2], aw_[2];
  const unsigned short* bsrc[2];
#pragma unroll
  for (int q = 0; q < 2; ++q) {
    int e = q * 256 + tid;
    arow[q] = e >> 2;
    akl[q]  = (e & 3) * 8;
    int m = m0 + arow[q];
    aw_[q] = m % 100;
    ah_[q] = (m / 100) % 36;
    ab_[q] = m / 3600;
    bsrc[q] = w1t + (long)(n0 + arow[q]) * 4608 + akl[q];
  }

  f32x4 acc[4][4];
#pragma unroll
  for (int i = 0; i < 4; ++i)
#pragma unroll
    for (int j = 0; j < 4; ++j) acc[i][j] = (f32x4){0.f, 0.f, 0.f, 0.f};

  const int fr = lane & 15;
  const int fk = (lane >> 4) * 8;              // k-slice start (elems)
  const unsigned short* Alrd = Al + (wm * 64 + fr) * 32 + fk;
  const unsigned short* Blrd = Bl + (wn * 64 + fr) * 32 + fk;

  for (int k0 = 0; k0 < 4608; k0 += 32) {
    const int tap = k0 >> 9;
    const int ci0 = k0 & 511;
    const int dh = (tap / 3) * 4 - 4, dw = (tap % 3) * 4 - 4;
    unsigned int apk[2][4];
#pragma unroll
    for (int q = 0; q < 2; ++q) {
      int ih = ah_[q] + dh, iw = aw_[q] + dw;
      if ((unsigned)ih < 36u && (unsigned)iw < 100u) {
        const float* s = in + ((((long)ab_[q] * 36 + ih) * 100 + iw) << 9) + ci0 + akl[q];
        float4 v0 = *(const float4*)s;
        float4 v1 = *(const float4*)(s + 4);
        apk[q][0] = pk2(v0.x, v0.y); apk[q][1] = pk2(v0.z, v0.w);
        apk[q][2] = pk2(v1.x, v1.y); apk[q][3] = pk2(v1.z, v1.w);
      } else {
        apk[q][0] = apk[q][1] = apk[q][2] = apk[q][3] = 0u;
      }
    }
    __syncthreads();                     // previous iter's ds_reads complete
#pragma unroll
    for (int q = 0; q < 2; ++q) {
      *(uint4*)(Al + (q * 256 + tid) * 8) = *(uint4*)apk[q];
      gload_lds16(bsrc[q] + k0, Bl + (q * 256 + tid) * 8);
    }
    __syncthreads();                     // vmcnt(0)+lgkmcnt(0) drained by compiler
    bf16x8 af[4], bfr[4];
#pragma unroll
    for (int m = 0; m < 4; ++m) af[m]  = *(const bf16x8*)(Alrd + m * 16 * 32);
#pragma unroll
    for (int n = 0; n < 4; ++n) bfr[n] = *(const bf16x8*)(Blrd + n * 16 * 32);
#pragma unroll
    for (int m = 0; m < 4; ++m)
#pragma unroll
      for (int n = 0; n < 4; ++n)
        acc[m][n] = __builtin_amdgcn_mfma_f32_16x16x32_bf16(af[m], bfr[n], acc[m][n], 0, 0, 0);
  }
  const int r0 = (lane >> 4) * 4;
#pragma unroll
  for (int m = 0; m < 4; ++m) {
    int row = m0 + wm * 64 + m * 16 + r0;
#pragma unroll
    for (int n = 0; n < 4; ++n) {
      int col = n0 + wn * 64 + n * 16 + fr;
#pragma unroll
      for (int j = 0; j < 4; ++j)
        x1[(long)(row + j) * 1024 + col] = f2bf(acc[m][n][j]);
    }
  }
}

// ============================================================
// generic 128-wide-N bf16 GEMM (conv2): A (M,K), Bt (128,K), C (M,128) f32
// ============================================================
__global__ __launch_bounds__(256) void gemm_mfma_128(
    const unsigned short* __restrict__ A,
    const unsigned short* __restrict__ Bt,
    float* __restrict__ C, int K)
{
  __shared__ unsigned short Al[128 * 32];
  __shared__ unsigned short Bl[128 * 32];
  const int tid  = threadIdx.x;
  const int lane = tid & 63;
  const int wave = tid >> 6;
  const int wm = wave >> 1, wn = wave & 1;
  const int m0 = blockIdx.x * 128;

  int arow[2], akl[2];
  const unsigned short* asrc[2];
  const unsigned short* bsrc[2];
#pragma unroll
  for (int q = 0; q < 2; ++q) {
    int e = q * 256 + tid;
    arow[q] = e >> 2;
    akl[q]  = (e & 3) * 8;
    asrc[q] = A  + (long)(m0 + arow[q]) * K + akl[q];
    bsrc[q] = Bt + (long)arow[q] * K + akl[q];
  }

  f32x4 acc[4][4];
#pragma unroll
  for (int i = 0; i < 4; ++i)
#pragma unroll
    for (int j = 0; j < 4; ++j) acc[i][j] = (f32x4){0.f, 0.f, 0.f, 0.f};

  const int fr = lane & 15;
  const int fk = (lane >> 4) * 8;
  const unsigned short* Alrd = Al + (wm * 64 + fr) * 32 + fk;
  const unsigned short* Blrd = Bl + (wn * 64 + fr) * 32 + fk;

  for (int k0 = 0; k0 < K; k0 += 32) {
    __syncthreads();
#pragma unroll
    for (int q = 0; q < 2; ++q) {
      gload_lds16(asrc[q] + k0, Al + (q * 256 + tid) * 8);
      gload_lds16(bsrc[q] + k0, Bl + (q * 256 + tid) * 8);
    }
    __syncthreads();
    bf16x8 af[4], bfr[4];
#pragma unroll
    for (int m = 0; m < 4; ++m) af[m]  = *(const bf16x8*)(Alrd + m * 16 * 32);
#pragma unroll
    for (int n = 0; n < 4; ++n) bfr[n] = *(const bf16x8*)(Blrd + n * 16 * 32);
#pragma unroll
    for (int m = 0; m < 4; ++m)
#pragma unroll
      for (int n = 0; n < 4; ++n)
        acc[m][n] = __builtin_amdgcn_mfma_f32_16x16x32_bf16(af[m], bfr[n], acc[m][n], 0, 0, 0);
  }
  const int r0 = (lane >> 4) * 4;
#pragma unroll
  for (int m = 0; m < 4; ++m) {
    int row = m0 + wm * 64 + m * 16 + r0;
#pragma unroll
    for (int n = 0; n < 4; ++n) {
      int col = wn * 64 + n * 16 + fr;
#pragma unroll
      for (int j = 0; j < 4; ++j)
        C[(long)(row + j) * 128 + col] = acc[m][n][j];
    }
  }
}

// ---------------- per-channel stats over x1 (bf16) ----------------
__global__ __launch_bounds__(256) void stats1(const unsigned short* __restrict__ x1,
                                              float* __restrict__ sum, float* __restrict__ ssq)
{
  const int tid = threadIdx.x;
  const int c0 = tid * 4;
  float s0=0,s1=0,s2=0,s3=0,q0=0,q1=0,q2=0,q3=0;
  for (int r = blockIdx.x; r < NPOS; r += gridDim.x) {
    uint2 v = *(const uint2*)(x1 + (long)r * 1024 + c0);
    float f0 = bf2f(v.x & 0xffffu), f1 = bf2f(v.x >> 16);
    float f2 = bf2f(v.y & 0xffffu), f3 = bf2f(v.y >> 16);
    s0 += f0; q0 += f0*f0;  s1 += f1; q1 += f1*f1;
    s2 += f2; q2 += f2*f2;  s3 += f3; q3 += f3*f3;
  }
  atomicAdd(&sum[c0+0], s0); atomicAdd(&ssq[c0+0], q0);
  atomicAdd(&sum[c0+1], s1); atomicAdd(&ssq[c0+1], q1);
  atomicAdd(&sum[c0+2], s2); atomicAdd(&ssq[c0+2], q2);
  atomicAdd(&sum[c0+3], s3); atomicAdd(&ssq[c0+3], q3);
}

__global__ void finalize_bn(const float* __restrict__ sum, const float* __restrict__ ssq,
                            const float* __restrict__ scale, const float* __restrict__ bias,
                            float* __restrict__ ab, int C, float invN)
{
  int c = blockIdx.x * blockDim.x + threadIdx.x;
  if (c >= C) return;
  float mean = sum[c] * invN;
  float var  = ssq[c] * invN - mean * mean;
  float a = scale[c] * rsqrtf(var + 1e-5f);
  ab[c] = a;
  ab[C + c] = bias[c] - mean * a;
}

// ---------------- relu(bn1(x1)) in place on bf16 x1 ----------------
__global__ __launch_bounds__(256) void bnrelu_x1(unsigned short* __restrict__ x1,
                                                 const float* __restrict__ ab)
{
  long base = ((long)blockIdx.x * 256 + threadIdx.x) * 8;
  int c0 = (int)(base & 1023);
  uint4 v = *(uint4*)(x1 + base);
  unsigned int w[4] = {v.x, v.y, v.z, v.w};
  unsigned int o[4];
#pragma unroll
  for (int j = 0; j < 4; ++j) {
    int c = c0 + j * 2;
    float lo = bf2f((unsigned short)(w[j] & 0xffffu));
    float hi = bf2f((unsigned short)(w[j] >> 16));
    lo = fmaxf(fmaf(lo, ab[c],     ab[1024 + c]),     0.f);
    hi = fmaxf(fmaf(hi, ab[c + 1], ab[1024 + c + 1]), 0.f);
    o[j] = pk2(lo, hi);
  }
  *(uint4*)(x1 + base) = make_uint4(o[0], o[1], o[2], o[3]);
}

// ---------------- stats over x2 (fp32, 128 ch) ----------------
__global__ __launch_bounds__(256) void stats2(const float* __restrict__ x2,
                                              float* __restrict__ sum, float* __restrict__ ssq)
{
  const int c = threadIdx.x & 127;
  const int g = threadIdx.x >> 7;
  float s = 0.f, q = 0.f;
  for (int r = blockIdx.x * 2 + g; r < NPOS; r += gridDim.x * 2) {
    float v = x2[(long)r * 128 + c];
    s += v; q += v * v;
  }
  atomicAdd(&sum[c], s); atomicAdd(&ssq[c], q);
}

// ---------------- apply bn2 + relu in place ----------------
__global__ __launch_bounds__(256) void apply_bn(float* __restrict__ x, const float* __restrict__ ab)
{
  int idx = (blockIdx.x * 256 + threadIdx.x) * 4;
  if (idx >= NPOS * 128) return;
  int c = idx & 127;
  float4 v = *(float4*)(x + idx);
  v.x = fmaxf(fmaf(v.x, ab[c+0], ab[128+c+0]), 0.f);
  v.y = fmaxf(fmaf(v.y, ab[c+1], ab[128+c+1]), 0.f);
  v.z = fmaxf(fmaf(v.z, ab[c+2], ab[128+c+2]), 0.f);
  v.w = fmaxf(fmaf(v.w, ab[c+3], ab[128+c+3]), 0.f);
  *(float4*)(x + idx) = v;
}

// ---------------- message-passing step (unchanged this round) ----------------
__global__ __launch_bounds__(256) void mp_step(
    float* __restrict__ x, const float* __restrict__ W,
    int in_off, int out_off, int L, int strideP)
{
  __shared__ float lds[16 * 128];
  const int b = blockIdx.y;
  const int p0 = blockIdx.x * 8;
  const int tid = threadIdx.x;
  const int co = tid & 127;
  const int pg = tid >> 7;
  const float* inb = x + in_off + b * 460800;
#pragma unroll
  for (int t = 0; t < 2; ++t) {
    int idx = tid + t * 256;
    int r = idx >> 5, q = idx & 31;
    int p = p0 - 4 + r;
    float4 v = make_float4(0.f, 0.f, 0.f, 0.f);
    if ((unsigned)p < (unsigned)L)
      v = *(const float4*)(inb + (long)p * strideP + q * 4);
    *(float4*)&lds[r * 128 + q * 4] = v;
  }
  __syncthreads();
  float a0=0.f, a1=0.f, a2=0.f, a3=0.f;
  const float* wbase = W + co;
#pragma unroll
  for (int k = 0; k < 9; ++k) {
    const float* lrow = &lds[(pg*4 + k) * 128];
    const float* wk = wbase + k * 16384;
#pragma unroll 4
    for (int ci = 0; ci < 128; ++ci) {
      float wv = wk[ci * 128];
      a0 = fmaf(lrow[ci      ], wv, a0);
      a1 = fmaf(lrow[ci + 128], wv, a1);
      a2 = fmaf(lrow[ci + 256], wv, a2);
      a3 = fmaf(lrow[ci + 384], wv, a3);
    }
  }
  float* outb = x + out_off + b * 460800;
  int pb = p0 + pg * 4;
  if (pb + 0 < L) outb[(long)(pb+0) * strideP + co] += fmaxf(a0, 0.f);
  if (pb + 1 < L) outb[(long)(pb+1) * strideP + co] += fmaxf(a1, 0.f);
  if (pb + 2 < L) outb[(long)(pb+2) * strideP + co] += fmaxf(a2, 0.f);
  if (pb + 3 < L) outb[(long)(pb+3) * strideP + co] += fmaxf(a3, 0.f);
}

// ---------------- segmentation head: 128 -> 5 + bias ----------------
__global__ __launch_bounds__(256) void seg_head(
    const float* __restrict__ xn, const float* __restrict__ w_seg,
    const float* __restrict__ b_seg, float* __restrict__ logits)
{
  __shared__ float ws[128 * 5];
  __shared__ float xs[32][129];
  const int tid = threadIdx.x;
  for (int i = tid; i < 640; i += 256) ws[i] = w_seg[i];
  const int pos0 = blockIdx.x * 32;
  for (int idx = tid; idx < 32 * 32; idx += 256) {
    int r = idx >> 5, q = idx & 31;
    float4 v = *(const float4*)(xn + (long)(pos0 + r) * 128 + q * 4);
    xs[r][q*4+0]=v.x; xs[r][q*4+1]=v.y; xs[r][q*4+2]=v.z; xs[r][q*4+3]=v.w;
  }
  __syncthreads();
  int r = tid >> 3, f = tid & 7;
  if (f < 5) {
    float acc = b_seg[f];
#pragma unroll 4
    for (int ci = 0; ci < 128; ++ci) acc = fmaf(xs[r][ci], ws[ci*5 + f], acc);
    logits[(long)(pos0 + r) * 5 + f] = acc;
  }
}

// ---------------- softmax + 2x2 mean pool ----------------
__global__ __launch_bounds__(256) void softpool(const float* __restrict__ logits, float* __restrict__ p)
{
  int idx = blockIdx.x * 256 + threadIdx.x;
  if (idx >= 16 * 18 * 50) return;
  int ww = idx % 50, hh = (idx / 50) % 18, b = idx / 900;
  float avg[5] = {0,0,0,0,0};
#pragma unroll
  for (int i = 0; i < 2; ++i)
#pragma unroll
    for (int j = 0; j < 2; ++j) {
      const float* L = logits + ((long)((b*36 + hh*2 + i) * 100) + ww*2 + j) * 5;
      float l0=L[0], l1=L[1], l2=L[2], l3=L[3], l4=L[4];
      float m = fmaxf(fmaxf(fmaxf(l0,l1), fmaxf(l2,l3)), l4);
      float e0=expf(l0-m), e1=expf(l1-m), e2=expf(l2-m), e3=expf(l3-m), e4=expf(l4-m);
      float inv = 1.f / (e0+e1+e2+e3+e4);
      avg[0] += e0*inv; avg[1] += e1*inv; avg[2] += e2*inv; avg[3] += e3*inv; avg[4] += e4*inv;
    }
  float* dst = p + (long)b * 4500 + (hh * 50 + ww) * 5;
#pragma unroll
  for (int f = 0; f < 5; ++f) dst[f] = avg[f] * 0.25f;
}

// ---------------- fc1 ----------------
__global__ __launch_bounds__(128) void fc1_kernel(
    const float* __restrict__ p, const float* __restrict__ w,
    const float* __restrict__ bias, float* __restrict__ z)
{
  __shared__ float ps[4500];
  const int b = blockIdx.x, tid = threadIdx.x;
  for (int i = tid; i < 4500; i += 128) ps[i] = p[(long)b * 4500 + i];
  __syncthreads();
  float acc = bias[tid];
#pragma unroll 4
  for (int m = 0; m < 4500; ++m) acc = fmaf(ps[m], w[(long)m * 128 + tid], acc);
  z[b * 128 + tid] = fmaxf(acc, 0.f);
}

// ---------------- fc2 ----------------
__global__ void fc2_kernel(const float* __restrict__ z, const float* __restrict__ w,
                           const float* __restrict__ bias, float* __restrict__ out)
{
  int t = threadIdx.x;
  if (t >= 64) return;
  int b = t >> 2, j = t & 3;
  float acc = bias[j];
#pragma unroll 4
  for (int n = 0; n < 128; ++n) acc = fmaf(z[b*128 + n], w[n*4 + j], acc);
  out[b*4 + j] = acc;
}

// ---------------- 8x bilinear resize ----------------
__global__ __launch_bounds__(256) void resize_bilinear(
    const float* __restrict__ logits, float* __restrict__ out)
{
  int idx = blockIdx.x * 256 + threadIdx.x;
  if (idx >= 18432000) return;
  int f = idx % 5;
  int t = idx / 5;
  int ow = t % 800; t /= 800;
  int oh = t % 288;
  int b = t / 288;
  float sh = (oh + 0.5f) * 0.125f - 0.5f;
  float sw = (ow + 0.5f) * 0.125f - 0.5f;
  int h0 = (int)floorf(sh); float fh = sh - (float)h0;
  int w0 = (int)floorf(sw); float fw = sw - (float)w0;
  int h1 = min(h0 + 1, 35); h0 = max(h0, 0);
  int w1 = min(w0 + 1, 99); w0 = max(w0, 0);
  const float* Lb = logits + (long)b * 36 * 100 * 5 + f;
  float v00 = Lb[(h0*100 + w0)*5], v01 = Lb[(h0*100 + w1)*5];
  float v10 = Lb[(h1*100 + w0)*5], v11 = Lb[(h1*100 + w1)*5];
  float v = (1.f-fh) * ((1.f-fw)*v00 + fw*v01) + fh * ((1.f-fw)*v10 + fw*v11);
  out[idx] = v;
}

// ============================================================
extern "C" void kernel_launch(void* const* d_in, const int* in_sizes, int n_in,
                              void* d_out, int out_size, void* d_ws, size_t ws_size,
                              hipStream_t stream)
{
  (void)in_sizes; (void)n_in; (void)out_size; (void)ws_size;
  const float* features = (const float*)d_in[0];
  const float* w_conv1  = (const float*)d_in[1];
  const float* bn1_s    = (const float*)d_in[2];
  const float* bn1_b    = (const float*)d_in[3];
  const float* w_conv2  = (const float*)d_in[4];
  const float* bn2_s    = (const float*)d_in[5];
  const float* bn2_b    = (const float*)d_in[6];
  const float* w_vf     = (const float*)d_in[7];
  const float* w_vr     = (const float*)d_in[8];
  const float* w_hf     = (const float*)d_in[9];
  const float* w_hr     = (const float*)d_in[10];
  const float* w_seg    = (const float*)d_in[11];
  const float* b_seg    = (const float*)d_in[12];
  const float* w_fc1    = (const float*)d_in[13];
  const float* b_fc1    = (const float*)d_in[14];
  const float* w_fc2    = (const float*)d_in[15];
  const float* b_fc2    = (const float*)d_in[16];

  char* ws = (char*)d_ws;
  unsigned short* x1  = (unsigned short*)ws;            // 117,964,800 B bf16
  // w1t lives in x2's region: dead before conv2 writes x2
  unsigned short* w1t = (unsigned short*)(ws + 117964800);  // 9,437,184 B
  float* x2     = (float*)(ws + 117964800);             // 29,491,200 B f32
  float* logits = (float*)(ws + 147456000);             // 1,152,000 B
  float* pbuf   = (float*)(ws + 148608000);             // 288,000 B
  float* zbuf   = (float*)(ws + 148896000);             // 8,192 B
  float* stats  = (float*)(ws + 148904192);             // 9,216 B
  float* ab1    = (float*)(ws + 148913408);             // 8,192 B
  float* ab2    = (float*)(ws + 148921600);             // 1,024 B
  unsigned short* w2t = (unsigned short*)(ws + 148922624); // 262,144 B
  float* outf   = (float*)d_out;

  hipMemsetAsync(stats, 0, 2304 * sizeof(float), stream);
  convert_w1t<<<2304, 256, 0, stream>>>(w_conv1, w1t);
  convert_w2t<<<64, 256, 0, stream>>>(w_conv2, w2t);

  conv1_mfma<<<dim3(8, 450), 256, 0, stream>>>(features, w1t, x1);
  stats1<<<512, 256, 0, stream>>>(x1, stats, stats + 1024);
  finalize_bn<<<4, 256, 0, stream>>>(stats, stats + 1024, bn1_s, bn1_b, ab1, 1024, 1.0f/57600.0f);
  bnrelu_x1<<<28800, 256, 0, stream>>>(x1, ab1);
  gemm_mfma_128<<<450, 256, 0, stream>>>(x1, w2t, x2, 1024);
  stats2<<<256, 256, 0, stream>>>(x2, stats + 2048, stats + 2176);
  finalize_bn<<<1, 128, 0, stream>>>(stats + 2048, stats + 2176, bn2_s, bn2_b, ab2, 128, 1.0f/57600.0f);
  apply_bn<<<7200, 256, 0, stream>>>(x2, ab2);

  for (int i = 1; i < 36; ++i)
    mp_step<<<dim3(13, NB), 256, 0, stream>>>(x2, w_vf, (i-1)*12800, i*12800, 100, 128);
  for (int i = 34; i >= 0; --i)
    mp_step<<<dim3(13, NB), 256, 0, stream>>>(x2, w_vr, (i+1)*12800, i*12800, 100, 128);
  for (int j = 1; j < 100; ++j)
    mp_step<<<dim3(5, NB), 256, 0, stream>>>(x2, w_hf, (j-1)*128, j*128, 36, 12800);
  for (int j = 98; j >= 0; --j)
    mp_step<<<dim3(5, NB), 256, 0, stream>>>(x2, w_hr, (j+1)*128, j*128, 36, 12800);

  seg_head<<<1800, 256, 0, stream>>>(x2, w_seg, b_seg, logits);
  softpool<<<57, 256, 0, stream>>>(logits, pbuf);
  fc1_kernel<<<16, 128, 0, stream>>>(pbuf, w_fc1, b_fc1, zbuf);
  fc2_kernel<<<1, 64, 0, stream>>>(zbuf, w_fc2, b_fc2, outf + 18432000);
  resize_bilinear<<<72000, 256, 0, stream>>>(logits, outf);
}

// Round 3
// 8181.356 us; speedup vs baseline: 2.6654x; 1.7280x over previous
//
#include <hip/hip_runtime.h>
#include <hip/hip_bf16.h>

#define NB 16
#define NPOS 57600

typedef short bf16x8 __attribute__((ext_vector_type(8)));
typedef float f32x4 __attribute__((ext_vector_type(4)));

__device__ __forceinline__ float bf2f(unsigned short u) {
  union { unsigned int i; float f; } c; c.i = ((unsigned int)u) << 16; return c.f;
}
// round-to-nearest-even f32 -> bf16 bits
__device__ __forceinline__ unsigned short f2bf(float f) {
  union { float f; unsigned int i; } c; c.f = f;
  unsigned int x = c.i;
  x += 0x7fffu + ((x >> 16) & 1u);
  return (unsigned short)(x >> 16);
}
__device__ __forceinline__ unsigned int pk2(float lo, float hi) {
  return (unsigned int)f2bf(lo) | ((unsigned int)f2bf(hi) << 16);
}

__device__ __forceinline__ void gload_lds16(const void* g, void* l) {
  __builtin_amdgcn_global_load_lds(
      (const __attribute__((address_space(1))) unsigned int*)(g),
      (__attribute__((address_space(3))) unsigned int*)(l), 16, 0, 0);
}

// ---------------- weight conversions (one-time, tiny) ----------------
// w1 (4608,1024) f32 -> w1t (1024,4608) bf16
__global__ __launch_bounds__(256) void convert_w1t(const float* __restrict__ w,
                                                   unsigned short* __restrict__ wt)
{
  int idx = blockIdx.x * 256 + threadIdx.x;     // 589824 jobs
  int n = idx & 1023;
  int k0 = (idx >> 10) * 8;
  unsigned int o[4];
#pragma unroll
  for (int j = 0; j < 4; ++j) {
    float lo = w[(long)(k0 + 2*j)     * 1024 + n];
    float hi = w[(long)(k0 + 2*j + 1) * 1024 + n];
    o[j] = pk2(lo, hi);
  }
  *(uint4*)(wt + (long)n * 4608 + k0) = make_uint4(o[0], o[1], o[2], o[3]);
}

// w2 (1024,128) f32 -> w2t (128,1024) bf16
__global__ __launch_bounds__(256) void convert_w2t(const float* __restrict__ w,
                                                   unsigned short* __restrict__ wt)
{
  int idx = blockIdx.x * 256 + threadIdx.x;     // 16384 jobs
  int n = idx & 127;
  int k0 = (idx >> 7) * 8;
  unsigned int o[4];
#pragma unroll
  for (int j = 0; j < 4; ++j) {
    float lo = w[(long)(k0 + 2*j)     * 128 + n];
    float hi = w[(long)(k0 + 2*j + 1) * 128 + n];
    o[j] = pk2(lo, hi);
  }
  *(uint4*)(wt + (long)n * 1024 + k0) = make_uint4(o[0], o[1], o[2], o[3]);
}

// w_mp (9,128,128)[tap][ci][co] f32 -> wt (128,1152)[co][tap*128+ci] bf16
__global__ __launch_bounds__(256) void convert_wmp(const float* __restrict__ w,
                                                   unsigned short* __restrict__ wt)
{
  int idx = blockIdx.x * 256 + threadIdx.x;     // 18432 jobs
  if (idx >= 18432) return;
  int co = idx & 127;
  int kg = idx >> 7;                            // 0..143
  int k0 = kg * 8;
  int tap = k0 >> 7, ci0 = k0 & 127;
  const float* src = w + (long)tap * 16384 + (long)ci0 * 128 + co;
  unsigned int o[4];
#pragma unroll
  for (int j = 0; j < 4; ++j)
    o[j] = pk2(src[(2*j) * 128], src[(2*j+1) * 128]);
  *(uint4*)(wt + (long)co * 1152 + k0) = make_uint4(o[0], o[1], o[2], o[3]);
}

// ============================================================
// conv1 via MFMA: implicit-im2col GEMM M=57600, K=4608, N=1024
// ============================================================
__global__ __launch_bounds__(256) void conv1_mfma(
    const float* __restrict__ in,            // (16,36,100,512) f32
    const unsigned short* __restrict__ w1t,  // (1024,4608) bf16 [n][k]
    unsigned short* __restrict__ x1)         // (57600,1024) bf16
{
  __shared__ unsigned short Al[128 * 32];
  __shared__ unsigned short Bl[128 * 32];
  const int tid  = threadIdx.x;
  const int lane = tid & 63;
  const int wave = tid >> 6;
  const int wm = wave >> 1, wn = wave & 1;
  const int m0 = blockIdx.y * 128;
  const int n0 = blockIdx.x * 128;

  int arow[2], akl[2], ab_[2], ah_[2], aw_[2];
  const unsigned short* bsrc[2];
#pragma unroll
  for (int q = 0; q < 2; ++q) {
    int e = q * 256 + tid;
    arow[q] = e >> 2;
    akl[q]  = (e & 3) * 8;
    int m = m0 + arow[q];
    aw_[q] = m % 100;
    ah_[q] = (m / 100) % 36;
    ab_[q] = m / 3600;
    bsrc[q] = w1t + (long)(n0 + arow[q]) * 4608 + akl[q];
  }

  f32x4 acc[4][4];
#pragma unroll
  for (int i = 0; i < 4; ++i)
#pragma unroll
    for (int j = 0; j < 4; ++j) acc[i][j] = (f32x4){0.f, 0.f, 0.f, 0.f};

  const int fr = lane & 15;
  const int fk = (lane >> 4) * 8;
  const unsigned short* Alrd = Al + (wm * 64 + fr) * 32 + fk;
  const unsigned short* Blrd = Bl + (wn * 64 + fr) * 32 + fk;

  for (int k0 = 0; k0 < 4608; k0 += 32) {
    const int tap = k0 >> 9;
    const int ci0 = k0 & 511;
    const int dh = (tap / 3) * 4 - 4, dw = (tap % 3) * 4 - 4;
    unsigned int apk[2][4];
#pragma unroll
    for (int q = 0; q < 2; ++q) {
      int ih = ah_[q] + dh, iw = aw_[q] + dw;
      if ((unsigned)ih < 36u && (unsigned)iw < 100u) {
        const float* s = in + ((((long)ab_[q] * 36 + ih) * 100 + iw) << 9) + ci0 + akl[q];
        float4 v0 = *(const float4*)s;
        float4 v1 = *(const float4*)(s + 4);
        apk[q][0] = pk2(v0.x, v0.y); apk[q][1] = pk2(v0.z, v0.w);
        apk[q][2] = pk2(v1.x, v1.y); apk[q][3] = pk2(v1.z, v1.w);
      } else {
        apk[q][0] = apk[q][1] = apk[q][2] = apk[q][3] = 0u;
      }
    }
    __syncthreads();
#pragma unroll
    for (int q = 0; q < 2; ++q) {
      *(uint4*)(Al + (q * 256 + tid) * 8) = *(uint4*)apk[q];
      gload_lds16(bsrc[q] + k0, Bl + (q * 256 + tid) * 8);
    }
    __syncthreads();
    bf16x8 af[4], bfr[4];
#pragma unroll
    for (int m = 0; m < 4; ++m) af[m]  = *(const bf16x8*)(Alrd + m * 16 * 32);
#pragma unroll
    for (int n = 0; n < 4; ++n) bfr[n] = *(const bf16x8*)(Blrd + n * 16 * 32);
#pragma unroll
    for (int m = 0; m < 4; ++m)
#pragma unroll
      for (int n = 0; n < 4; ++n)
        acc[m][n] = __builtin_amdgcn_mfma_f32_16x16x32_bf16(af[m], bfr[n], acc[m][n], 0, 0, 0);
  }
  const int r0 = (lane >> 4) * 4;
#pragma unroll
  for (int m = 0; m < 4; ++m) {
    int row = m0 + wm * 64 + m * 16 + r0;
#pragma unroll
    for (int n = 0; n < 4; ++n) {
      int col = n0 + wn * 64 + n * 16 + fr;
#pragma unroll
      for (int j = 0; j < 4; ++j)
        x1[(long)(row + j) * 1024 + col] = f2bf(acc[m][n][j]);
    }
  }
}

// ============================================================
// conv2: bf16 GEMM A(M,1024) x Bt(128,1024) -> C(M,128) f32
// ============================================================
__global__ __launch_bounds__(256) void gemm_mfma_128(
    const unsigned short* __restrict__ A,
    const unsigned short* __restrict__ Bt,
    float* __restrict__ C, int K)
{
  __shared__ unsigned short Al[128 * 32];
  __shared__ unsigned short Bl[128 * 32];
  const int tid  = threadIdx.x;
  const int lane = tid & 63;
  const int wave = tid >> 6;
  const int wm = wave >> 1, wn = wave & 1;
  const int m0 = blockIdx.x * 128;

  int arow[2], akl[2];
  const unsigned short* asrc[2];
  const unsigned short* bsrc[2];
#pragma unroll
  for (int q = 0; q < 2; ++q) {
    int e = q * 256 + tid;
    arow[q] = e >> 2;
    akl[q]  = (e & 3) * 8;
    asrc[q] = A  + (long)(m0 + arow[q]) * K + akl[q];
    bsrc[q] = Bt + (long)arow[q] * K + akl[q];
  }

  f32x4 acc[4][4];
#pragma unroll
  for (int i = 0; i < 4; ++i)
#pragma unroll
    for (int j = 0; j < 4; ++j) acc[i][j] = (f32x4){0.f, 0.f, 0.f, 0.f};

  const int fr = lane & 15;
  const int fk = (lane >> 4) * 8;
  const unsigned short* Alrd = Al + (wm * 64 + fr) * 32 + fk;
  const unsigned short* Blrd = Bl + (wn * 64 + fr) * 32 + fk;

  for (int k0 = 0; k0 < K; k0 += 32) {
    __syncthreads();
#pragma unroll
    for (int q = 0; q < 2; ++q) {
      gload_lds16(asrc[q] + k0, Al + (q * 256 + tid) * 8);
      gload_lds16(bsrc[q] + k0, Bl + (q * 256 + tid) * 8);
    }
    __syncthreads();
    bf16x8 af[4], bfr[4];
#pragma unroll
    for (int m = 0; m < 4; ++m) af[m]  = *(const bf16x8*)(Alrd + m * 16 * 32);
#pragma unroll
    for (int n = 0; n < 4; ++n) bfr[n] = *(const bf16x8*)(Blrd + n * 16 * 32);
#pragma unroll
    for (int m = 0; m < 4; ++m)
#pragma unroll
      for (int n = 0; n < 4; ++n)
        acc[m][n] = __builtin_amdgcn_mfma_f32_16x16x32_bf16(af[m], bfr[n], acc[m][n], 0, 0, 0);
  }
  const int r0 = (lane >> 4) * 4;
#pragma unroll
  for (int m = 0; m < 4; ++m) {
    int row = m0 + wm * 64 + m * 16 + r0;
#pragma unroll
    for (int n = 0; n < 4; ++n) {
      int col = wn * 64 + n * 16 + fr;
#pragma unroll
      for (int j = 0; j < 4; ++j)
        C[(long)(row + j) * 128 + col] = acc[m][n][j];
    }
  }
}

// ---------------- per-channel stats over x1 (bf16) ----------------
__global__ __launch_bounds__(256) void stats1(const unsigned short* __restrict__ x1,
                                              float* __restrict__ sum, float* __restrict__ ssq)
{
  const int tid = threadIdx.x;
  const int c0 = tid * 4;
  float s0=0,s1=0,s2=0,s3=0,q0=0,q1=0,q2=0,q3=0;
  for (int r = blockIdx.x; r < NPOS; r += gridDim.x) {
    uint2 v = *(const uint2*)(x1 + (long)r * 1024 + c0);
    float f0 = bf2f(v.x & 0xffffu), f1 = bf2f(v.x >> 16);
    float f2 = bf2f(v.y & 0xffffu), f3 = bf2f(v.y >> 16);
    s0 += f0; q0 += f0*f0;  s1 += f1; q1 += f1*f1;
    s2 += f2; q2 += f2*f2;  s3 += f3; q3 += f3*f3;
  }
  atomicAdd(&sum[c0+0], s0); atomicAdd(&ssq[c0+0], q0);
  atomicAdd(&sum[c0+1], s1); atomicAdd(&ssq[c0+1], q1);
  atomicAdd(&sum[c0+2], s2); atomicAdd(&ssq[c0+2], q2);
  atomicAdd(&sum[c0+3], s3); atomicAdd(&ssq[c0+3], q3);
}

__global__ void finalize_bn(const float* __restrict__ sum, const float* __restrict__ ssq,
                            const float* __restrict__ scale, const float* __restrict__ bias,
                            float* __restrict__ ab, int C, float invN)
{
  int c = blockIdx.x * blockDim.x + threadIdx.x;
  if (c >= C) return;
  float mean = sum[c] * invN;
  float var  = ssq[c] * invN - mean * mean;
  float a = scale[c] * rsqrtf(var + 1e-5f);
  ab[c] = a;
  ab[C + c] = bias[c] - mean * a;
}

// ---------------- relu(bn1(x1)) in place on bf16 x1 ----------------
__global__ __launch_bounds__(256) void bnrelu_x1(unsigned short* __restrict__ x1,
                                                 const float* __restrict__ ab)
{
  long base = ((long)blockIdx.x * 256 + threadIdx.x) * 8;
  int c0 = (int)(base & 1023);
  uint4 v = *(uint4*)(x1 + base);
  unsigned int w[4] = {v.x, v.y, v.z, v.w};
  unsigned int o[4];
#pragma unroll
  for (int j = 0; j < 4; ++j) {
    int c = c0 + j * 2;
    float lo = bf2f((unsigned short)(w[j] & 0xffffu));
    float hi = bf2f((unsigned short)(w[j] >> 16));
    lo = fmaxf(fmaf(lo, ab[c],     ab[1024 + c]),     0.f);
    hi = fmaxf(fmaf(hi, ab[c + 1], ab[1024 + c + 1]), 0.f);
    o[j] = pk2(lo, hi);
  }
  *(uint4*)(x1 + base) = make_uint4(o[0], o[1], o[2], o[3]);
}

// ---------------- stats over x2 (fp32, 128 ch) ----------------
__global__ __launch_bounds__(256) void stats2(const float* __restrict__ x2,
                                              float* __restrict__ sum, float* __restrict__ ssq)
{
  const int c = threadIdx.x & 127;
  const int g = threadIdx.x >> 7;
  float s = 0.f, q = 0.f;
  for (int r = blockIdx.x * 2 + g; r < NPOS; r += gridDim.x * 2) {
    float v = x2[(long)r * 128 + c];
    s += v; q += v * v;
  }
  atomicAdd(&sum[c], s); atomicAdd(&ssq[c], q);
}

// ---------------- apply bn2 + relu in place ----------------
__global__ __launch_bounds__(256) void apply_bn(float* __restrict__ x, const float* __restrict__ ab)
{
  int idx = (blockIdx.x * 256 + threadIdx.x) * 4;
  if (idx >= NPOS * 128) return;
  int c = idx & 127;
  float4 v = *(float4*)(x + idx);
  v.x = fmaxf(fmaf(v.x, ab[c+0], ab[128+c+0]), 0.f);
  v.y = fmaxf(fmaf(v.y, ab[c+1], ab[128+c+1]), 0.f);
  v.z = fmaxf(fmaf(v.z, ab[c+2], ab[128+c+2]), 0.f);
  v.w = fmaxf(fmaf(v.w, ab[c+3], ab[128+c+3]), 0.f);
  *(float4*)(x + idx) = v;
}

// ============================================================
// Fused message passing: one block per batch, whole directional
// scan in one launch. Active row double-buffered in LDS (bf16,
// XOR-swizzled); weights (bf16, [co][k]) streamed from L2;
// MFMA per step: M=Lpad, K=1152, N=128. 4 waves: 2 (m) x 2 (n).
// step: x2[row i] += relu(conv1d(row i-di)); new row -> LDS.
// ============================================================
#define MPROWS 120
#define MPBUF (MPROWS * 128)   // halfwords per buffer
__global__ __launch_bounds__(256) void mp_fused(
    float* __restrict__ x2, const unsigned short* __restrict__ wt,
    const int L, const int posStride, const int rowStride,
    const int i0, const int di, const int nsteps)
{
  __shared__ unsigned short rowbuf[2 * MPBUF];   // 61440 B
  const int tid  = threadIdx.x;
  const int lane = tid & 63;
  const int wave = tid >> 6;        // 0..3
  const int wm = wave >> 1;         // m-group 0..1
  const int wn = wave & 1;          // n-half 0..1
  const int fr = lane & 15;
  const int ks = lane >> 4;         // 0..3 (k-slice / row-quad)
  float* xb = x2 + (long)blockIdx.x * 460800;
  const int ntiles = (L + 15) >> 4;

  // zero both buffers (pads stay zero forever)
  for (int i = tid; i < (2 * MPBUF) / 8; i += 256)
    *(uint4*)(rowbuf + i * 8) = make_uint4(0u, 0u, 0u, 0u);
  __syncthreads();
  // load row i0 -> buf0 (bf16, swizzled); row i0 is never modified
  for (int e = tid * 4; e < L * 128; e += 1024) {
    int w = e >> 7, c = e & 127;
    float4 v = *(const float4*)(xb + (long)i0 * rowStride + (long)w * posStride + c);
    int br = w + 4;
    int byte = br * 256 + c * 2;
    byte ^= (br & 7) << 4;
    *(uint2*)((char*)rowbuf + byte) = make_uint2(pk2(v.x, v.y), pk2(v.z, v.w));
  }
  __syncthreads();

  // per-lane weight base: n = wn*64 + nf*16 + fr, k-slice ks*8
  const unsigned short* wb = wt + (long)(wn * 64 + fr) * 1152 + ks * 8;

  for (int s = 1; s <= nsteps; ++s) {
    const char* curb = (const char*)rowbuf + (((s & 1) ^ 1) * MPBUF) * 2;
    char* nxtb = (char*)rowbuf + ((s & 1) * MPBUF) * 2;
    const int i = i0 + s * di;

    f32x4 acc[4][4];
#pragma unroll
    for (int u = 0; u < 4; ++u)
#pragma unroll
      for (int n = 0; n < 4; ++n) acc[u][n] = (f32x4){0.f, 0.f, 0.f, 0.f};

    for (int k0 = 0; k0 < 1152; k0 += 32) {
      const int tap = k0 >> 7;
      const int colb = ((k0 & 127) + ks * 8) * 2;
      bf16x8 bfrag[4];
#pragma unroll
      for (int n = 0; n < 4; ++n)
        bfrag[n] = *(const bf16x8*)(wb + (long)n * 16 * 1152 + k0);
#pragma unroll
      for (int u = 0; u < 4; ++u) {
        const int t = wm + u * 2;
        if (t < ntiles) {
          int br = t * 16 + fr + tap;
          int byte = (br * 256 + colb) ^ ((br & 7) << 4);
          bf16x8 af = *(const bf16x8*)(curb + byte);
#pragma unroll
          for (int n = 0; n < 4; ++n)
            acc[u][n] = __builtin_amdgcn_mfma_f32_16x16x32_bf16(af, bfrag[n], acc[u][n], 0, 0, 0);
        }
      }
    }
    // epilogue: x2 += relu(acc); new row -> next LDS buffer
#pragma unroll
    for (int u = 0; u < 4; ++u) {
      const int t = wm + u * 2;
      if (t < ntiles) {
#pragma unroll
        for (int n = 0; n < 4; ++n) {
          const int col = wn * 64 + n * 16 + fr;
#pragma unroll
          for (int j = 0; j < 4; ++j) {
            const int m = t * 16 + ks * 4 + j;
            if (m < L) {
              long off = (long)i * rowStride + (long)m * posStride + col;
              float v = xb[off] + fmaxf(acc[u][n][j], 0.f);
              xb[off] = v;
              int br = m + 4;
              int byte = (br * 256 + col * 2) ^ ((br & 7) << 4);
              *(unsigned short*)(nxtb + byte) = f2bf(v);
            }
          }
        }
      }
    }
    __syncthreads();
  }
}

// ---------------- segmentation head: 128 -> 5 + bias ----------------
__global__ __launch_bounds__(256) void seg_head(
    const float* __restrict__ xn, const float* __restrict__ w_seg,
    const float* __restrict__ b_seg, float* __restrict__ logits)
{
  __shared__ float ws[128 * 5];
  __shared__ float xs[32][129];
  const int tid = threadIdx.x;
  for (int i = tid; i < 640; i += 256) ws[i] = w_seg[i];
  const int pos0 = blockIdx.x * 32;
  for (int idx = tid; idx < 32 * 32; idx += 256) {
    int r = idx >> 5, q = idx & 31;
    float4 v = *(const float4*)(xn + (long)(pos0 + r) * 128 + q * 4);
    xs[r][q*4+0]=v.x; xs[r][q*4+1]=v.y; xs[r][q*4+2]=v.z; xs[r][q*4+3]=v.w;
  }
  __syncthreads();
  int r = tid >> 3, f = tid & 7;
  if (f < 5) {
    float acc = b_seg[f];
#pragma unroll 4
    for (int ci = 0; ci < 128; ++ci) acc = fmaf(xs[r][ci], ws[ci*5 + f], acc);
    logits[(long)(pos0 + r) * 5 + f] = acc;
  }
}

// ---------------- softmax + 2x2 mean pool ----------------
__global__ __launch_bounds__(256) void softpool(const float* __restrict__ logits, float* __restrict__ p)
{
  int idx = blockIdx.x * 256 + threadIdx.x;
  if (idx >= 16 * 18 * 50) return;
  int ww = idx % 50, hh = (idx / 50) % 18, b = idx / 900;
  float avg[5] = {0,0,0,0,0};
#pragma unroll
  for (int i = 0; i < 2; ++i)
#pragma unroll
    for (int j = 0; j < 2; ++j) {
      const float* L = logits + ((long)((b*36 + hh*2 + i) * 100) + ww*2 + j) * 5;
      float l0=L[0], l1=L[1], l2=L[2], l3=L[3], l4=L[4];
      float m = fmaxf(fmaxf(fmaxf(l0,l1), fmaxf(l2,l3)), l4);
      float e0=expf(l0-m), e1=expf(l1-m), e2=expf(l2-m), e3=expf(l3-m), e4=expf(l4-m);
      float inv = 1.f / (e0+e1+e2+e3+e4);
      avg[0] += e0*inv; avg[1] += e1*inv; avg[2] += e2*inv; avg[3] += e3*inv; avg[4] += e4*inv;
    }
  float* dst = p + (long)b * 4500 + (hh * 50 + ww) * 5;
#pragma unroll
  for (int f = 0; f < 5; ++f) dst[f] = avg[f] * 0.25f;
}

// ---------------- fc1 ----------------
__global__ __launch_bounds__(128) void fc1_kernel(
    const float* __restrict__ p, const float* __restrict__ w,
    const float* __restrict__ bias, float* __restrict__ z)
{
  __shared__ float ps[4500];
  const int b = blockIdx.x, tid = threadIdx.x;
  for (int i = tid; i < 4500; i += 128) ps[i] = p[(long)b * 4500 + i];
  __syncthreads();
  float acc = bias[tid];
#pragma unroll 4
  for (int m = 0; m < 4500; ++m) acc = fmaf(ps[m], w[(long)m * 128 + tid], acc);
  z[b * 128 + tid] = fmaxf(acc, 0.f);
}

// ---------------- fc2 ----------------
__global__ void fc2_kernel(const float* __restrict__ z, const float* __restrict__ w,
                           const float* __restrict__ bias, float* __restrict__ out)
{
  int t = threadIdx.x;
  if (t >= 64) return;
  int b = t >> 2, j = t & 3;
  float acc = bias[j];
#pragma unroll 4
  for (int n = 0; n < 128; ++n) acc = fmaf(z[b*128 + n], w[n*4 + j], acc);
  out[b*4 + j] = acc;
}

// ---------------- 8x bilinear resize ----------------
__global__ __launch_bounds__(256) void resize_bilinear(
    const float* __restrict__ logits, float* __restrict__ out)
{
  int idx = blockIdx.x * 256 + threadIdx.x;
  if (idx >= 18432000) return;
  int f = idx % 5;
  int t = idx / 5;
  int ow = t % 800; t /= 800;
  int oh = t % 288;
  int b = t / 288;
  float sh = (oh + 0.5f) * 0.125f - 0.5f;
  float sw = (ow + 0.5f) * 0.125f - 0.5f;
  int h0 = (int)floorf(sh); float fh = sh - (float)h0;
  int w0 = (int)floorf(sw); float fw = sw - (float)w0;
  int h1 = min(h0 + 1, 35); h0 = max(h0, 0);
  int w1 = min(w0 + 1, 99); w0 = max(w0, 0);
  const float* Lb = logits + (long)b * 36 * 100 * 5 + f;
  float v00 = Lb[(h0*100 + w0)*5], v01 = Lb[(h0*100 + w1)*5];
  float v10 = Lb[(h1*100 + w0)*5], v11 = Lb[(h1*100 + w1)*5];
  float v = (1.f-fh) * ((1.f-fw)*v00 + fw*v01) + fh * ((1.f-fw)*v10 + fw*v11);
  out[idx] = v;
}

// ============================================================
extern "C" void kernel_launch(void* const* d_in, const int* in_sizes, int n_in,
                              void* d_out, int out_size, void* d_ws, size_t ws_size,
                              hipStream_t stream)
{
  (void)in_sizes; (void)n_in; (void)out_size; (void)ws_size;
  const float* features = (const float*)d_in[0];
  const float* w_conv1  = (const float*)d_in[1];
  const float* bn1_s    = (const float*)d_in[2];
  const float* bn1_b    = (const float*)d_in[3];
  const float* w_conv2  = (const float*)d_in[4];
  const float* bn2_s    = (const float*)d_in[5];
  const float* bn2_b    = (const float*)d_in[6];
  const float* w_vf     = (const float*)d_in[7];
  const float* w_vr     = (const float*)d_in[8];
  const float* w_hf     = (const float*)d_in[9];
  const float* w_hr     = (const float*)d_in[10];
  const float* w_seg    = (const float*)d_in[11];
  const float* b_seg    = (const float*)d_in[12];
  const float* w_fc1    = (const float*)d_in[13];
  const float* b_fc1    = (const float*)d_in[14];
  const float* w_fc2    = (const float*)d_in[15];
  const float* b_fc2    = (const float*)d_in[16];

  char* ws = (char*)d_ws;
  unsigned short* x1  = (unsigned short*)ws;                // 117,964,800 B bf16
  unsigned short* w1t = (unsigned short*)(ws + 117964800);  // overlaps x2 (dead until conv2)
  float* x2     = (float*)(ws + 117964800);                 // 29,491,200 B f32
  float* logits = (float*)(ws + 147456000);                 // 1,152,000 B
  // wtmp overlaps logits+pbuf: dead until after MP (seg_head writes logits later)
  unsigned short* wtmp = (unsigned short*)(ws + 147456000); // 1,179,648 B (4 x 147456 hw)
  float* pbuf   = (float*)(ws + 148608000);                 // 288,000 B
  float* zbuf   = (float*)(ws + 148896000);                 // 8,192 B
  float* stats  = (float*)(ws + 148904192);                 // 9,216 B
  float* ab1    = (float*)(ws + 148913408);                 // 8,192 B
  float* ab2    = (float*)(ws + 148921600);                 // 1,024 B
  unsigned short* w2t = (unsigned short*)(ws + 148922624);  // 262,144 B
  float* outf   = (float*)d_out;

  hipMemsetAsync(stats, 0, 2304 * sizeof(float), stream);
  convert_w1t<<<2304, 256, 0, stream>>>(w_conv1, w1t);
  convert_w2t<<<64, 256, 0, stream>>>(w_conv2, w2t);
  convert_wmp<<<72, 256, 0, stream>>>(w_vf, wtmp + 0 * 147456);
  convert_wmp<<<72, 256, 0, stream>>>(w_vr, wtmp + 1 * 147456);
  convert_wmp<<<72, 256, 0, stream>>>(w_hf, wtmp + 2 * 147456);
  convert_wmp<<<72, 256, 0, stream>>>(w_hr, wtmp + 3 * 147456);

  conv1_mfma<<<dim3(8, 450), 256, 0, stream>>>(features, w1t, x1);
  stats1<<<512, 256, 0, stream>>>(x1, stats, stats + 1024);
  finalize_bn<<<4, 256, 0, stream>>>(stats, stats + 1024, bn1_s, bn1_b, ab1, 1024, 1.0f/57600.0f);
  bnrelu_x1<<<28800, 256, 0, stream>>>(x1, ab1);
  gemm_mfma_128<<<450, 256, 0, stream>>>(x1, w2t, x2, 1024);
  stats2<<<256, 256, 0, stream>>>(x2, stats + 2048, stats + 2176);
  finalize_bn<<<1, 128, 0, stream>>>(stats + 2048, stats + 2176, bn2_s, bn2_b, ab2, 128, 1.0f/57600.0f);
  apply_bn<<<7200, 256, 0, stream>>>(x2, ab2);

  // fused message passing: 4 launches (vf, vr, hf, hr)
  mp_fused<<<NB, 256, 0, stream>>>(x2, wtmp + 0 * 147456, 100, 128,   12800, 0,  +1, 35);
  mp_fused<<<NB, 256, 0, stream>>>(x2, wtmp + 1 * 147456, 100, 128,   12800, 35, -1, 35);
  mp_fused<<<NB, 256, 0, stream>>>(x2, wtmp + 2 * 147456, 36,  12800, 128,   0,  +1, 99);
  mp_fused<<<NB, 256, 0, stream>>>(x2, wtmp + 3 * 147456, 36,  12800, 128,   99, -1, 99);

  seg_head<<<1800, 256, 0, stream>>>(x2, w_seg, b_seg, logits);
  softpool<<<57, 256, 0, stream>>>(logits, pbuf);
  fc1_kernel<<<16, 128, 0, stream>>>(pbuf, w_fc1, b_fc1, zbuf);
  fc2_kernel<<<1, 64, 0, stream>>>(zbuf, w_fc2, b_fc2, outf + 18432000);
  resize_bilinear<<<72000, 256, 0, stream>>>(logits, outf);
}

// Round 4
// 4111.906 us; speedup vs baseline: 5.3033x; 1.9897x over previous
//
#include <hip/hip_runtime.h>
#include <hip/hip_bf16.h>

#define NB 16
#define NPOS 57600

typedef short bf16x8 __attribute__((ext_vector_type(8)));
typedef float f32x4 __attribute__((ext_vector_type(4)));

__device__ __forceinline__ float bf2f(unsigned short u) {
  union { unsigned int i; float f; } c; c.i = ((unsigned int)u) << 16; return c.f;
}
// round-to-nearest-even f32 -> bf16 bits
__device__ __forceinline__ unsigned short f2bf(float f) {
  union { float f; unsigned int i; } c; c.f = f;
  unsigned int x = c.i;
  x += 0x7fffu + ((x >> 16) & 1u);
  return (unsigned short)(x >> 16);
}
__device__ __forceinline__ unsigned int pk2(float lo, float hi) {
  return (unsigned int)f2bf(lo) | ((unsigned int)f2bf(hi) << 16);
}

__device__ __forceinline__ void gload_lds16(const void* g, void* l) {
  __builtin_amdgcn_global_load_lds(
      (const __attribute__((address_space(1))) unsigned int*)(g),
      (__attribute__((address_space(3))) unsigned int*)(l), 16, 0, 0);
}

// ---------------- weight conversions (one-time, tiny) ----------------
// w1 (4608,1024) f32 -> w1t (1024,4608) bf16
__global__ __launch_bounds__(256) void convert_w1t(const float* __restrict__ w,
                                                   unsigned short* __restrict__ wt)
{
  int idx = blockIdx.x * 256 + threadIdx.x;     // 589824 jobs
  int n = idx & 1023;
  int k0 = (idx >> 10) * 8;
  unsigned int o[4];
#pragma unroll
  for (int j = 0; j < 4; ++j) {
    float lo = w[(long)(k0 + 2*j)     * 1024 + n];
    float hi = w[(long)(k0 + 2*j + 1) * 1024 + n];
    o[j] = pk2(lo, hi);
  }
  *(uint4*)(wt + (long)n * 4608 + k0) = make_uint4(o[0], o[1], o[2], o[3]);
}

// w2 (1024,128) f32 -> w2t (128,1024) bf16
__global__ __launch_bounds__(256) void convert_w2t(const float* __restrict__ w,
                                                   unsigned short* __restrict__ wt)
{
  int idx = blockIdx.x * 256 + threadIdx.x;     // 16384 jobs
  int n = idx & 127;
  int k0 = (idx >> 7) * 8;
  unsigned int o[4];
#pragma unroll
  for (int j = 0; j < 4; ++j) {
    float lo = w[(long)(k0 + 2*j)     * 128 + n];
    float hi = w[(long)(k0 + 2*j + 1) * 128 + n];
    o[j] = pk2(lo, hi);
  }
  *(uint4*)(wt + (long)n * 1024 + k0) = make_uint4(o[0], o[1], o[2], o[3]);
}

// w_mp (9,128,128)[tap][ci][co] f32 -> wt (128,1152)[co][tap*128+ci] bf16
__global__ __launch_bounds__(256) void convert_wmp(const float* __restrict__ w,
                                                   unsigned short* __restrict__ wt)
{
  int idx = blockIdx.x * 256 + threadIdx.x;     // 18432 jobs
  if (idx >= 18432) return;
  int co = idx & 127;
  int kg = idx >> 7;                            // 0..143
  int k0 = kg * 8;
  int tap = k0 >> 7, ci0 = k0 & 127;
  const float* src = w + (long)tap * 16384 + (long)ci0 * 128 + co;
  unsigned int o[4];
#pragma unroll
  for (int j = 0; j < 4; ++j)
    o[j] = pk2(src[(2*j) * 128], src[(2*j+1) * 128]);
  *(uint4*)(wt + (long)co * 1152 + k0) = make_uint4(o[0], o[1], o[2], o[3]);
}

// ============================================================
// conv1 via MFMA: implicit-im2col GEMM M=57600, K=4608, N=1024
// ============================================================
__global__ __launch_bounds__(256) void conv1_mfma(
    const float* __restrict__ in,            // (16,36,100,512) f32
    const unsigned short* __restrict__ w1t,  // (1024,4608) bf16 [n][k]
    unsigned short* __restrict__ x1)         // (57600,1024) bf16
{
  __shared__ unsigned short Al[128 * 32];
  __shared__ unsigned short Bl[128 * 32];
  const int tid  = threadIdx.x;
  const int lane = tid & 63;
  const int wave = tid >> 6;
  const int wm = wave >> 1, wn = wave & 1;
  const int m0 = blockIdx.y * 128;
  const int n0 = blockIdx.x * 128;

  int arow[2], akl[2], ab_[2], ah_[2], aw_[2];
  const unsigned short* bsrc[2];
#pragma unroll
  for (int q = 0; q < 2; ++q) {
    int e = q * 256 + tid;
    arow[q] = e >> 2;
    akl[q]  = (e & 3) * 8;
    int m = m0 + arow[q];
    aw_[q] = m % 100;
    ah_[q] = (m / 100) % 36;
    ab_[q] = m / 3600;
    bsrc[q] = w1t + (long)(n0 + arow[q]) * 4608 + akl[q];
  }

  f32x4 acc[4][4];
#pragma unroll
  for (int i = 0; i < 4; ++i)
#pragma unroll
    for (int j = 0; j < 4; ++j) acc[i][j] = (f32x4){0.f, 0.f, 0.f, 0.f};

  const int fr = lane & 15;
  const int fk = (lane >> 4) * 8;
  const unsigned short* Alrd = Al + (wm * 64 + fr) * 32 + fk;
  const unsigned short* Blrd = Bl + (wn * 64 + fr) * 32 + fk;

  for (int k0 = 0; k0 < 4608; k0 += 32) {
    const int tap = k0 >> 9;
    const int ci0 = k0 & 511;
    const int dh = (tap / 3) * 4 - 4, dw = (tap % 3) * 4 - 4;
    unsigned int apk[2][4];
#pragma unroll
    for (int q = 0; q < 2; ++q) {
      int ih = ah_[q] + dh, iw = aw_[q] + dw;
      if ((unsigned)ih < 36u && (unsigned)iw < 100u) {
        const float* s = in + ((((long)ab_[q] * 36 + ih) * 100 + iw) << 9) + ci0 + akl[q];
        float4 v0 = *(const float4*)s;
        float4 v1 = *(const float4*)(s + 4);
        apk[q][0] = pk2(v0.x, v0.y); apk[q][1] = pk2(v0.z, v0.w);
        apk[q][2] = pk2(v1.x, v1.y); apk[q][3] = pk2(v1.z, v1.w);
      } else {
        apk[q][0] = apk[q][1] = apk[q][2] = apk[q][3] = 0u;
      }
    }
    __syncthreads();
#pragma unroll
    for (int q = 0; q < 2; ++q) {
      *(uint4*)(Al + (q * 256 + tid) * 8) = *(uint4*)apk[q];
      gload_lds16(bsrc[q] + k0, Bl + (q * 256 + tid) * 8);
    }
    __syncthreads();
    bf16x8 af[4], bfr[4];
#pragma unroll
    for (int m = 0; m < 4; ++m) af[m]  = *(const bf16x8*)(Alrd + m * 16 * 32);
#pragma unroll
    for (int n = 0; n < 4; ++n) bfr[n] = *(const bf16x8*)(Blrd + n * 16 * 32);
#pragma unroll
    for (int m = 0; m < 4; ++m)
#pragma unroll
      for (int n = 0; n < 4; ++n)
        acc[m][n] = __builtin_amdgcn_mfma_f32_16x16x32_bf16(af[m], bfr[n], acc[m][n], 0, 0, 0);
  }
  const int r0 = (lane >> 4) * 4;
#pragma unroll
  for (int m = 0; m < 4; ++m) {
    int row = m0 + wm * 64 + m * 16 + r0;
#pragma unroll
    for (int n = 0; n < 4; ++n) {
      int col = n0 + wn * 64 + n * 16 + fr;
#pragma unroll
      for (int j = 0; j < 4; ++j)
        x1[(long)(row + j) * 1024 + col] = f2bf(acc[m][n][j]);
    }
  }
}

// ============================================================
// conv2: bf16 GEMM A(M,1024) x Bt(128,1024) -> C(M,128) f32
// ============================================================
__global__ __launch_bounds__(256) void gemm_mfma_128(
    const unsigned short* __restrict__ A,
    const unsigned short* __restrict__ Bt,
    float* __restrict__ C, int K)
{
  __shared__ unsigned short Al[128 * 32];
  __shared__ unsigned short Bl[128 * 32];
  const int tid  = threadIdx.x;
  const int lane = tid & 63;
  const int wave = tid >> 6;
  const int wm = wave >> 1, wn = wave & 1;
  const int m0 = blockIdx.x * 128;

  int arow[2], akl[2];
  const unsigned short* asrc[2];
  const unsigned short* bsrc[2];
#pragma unroll
  for (int q = 0; q < 2; ++q) {
    int e = q * 256 + tid;
    arow[q] = e >> 2;
    akl[q]  = (e & 3) * 8;
    asrc[q] = A  + (long)(m0 + arow[q]) * K + akl[q];
    bsrc[q] = Bt + (long)arow[q] * K + akl[q];
  }

  f32x4 acc[4][4];
#pragma unroll
  for (int i = 0; i < 4; ++i)
#pragma unroll
    for (int j = 0; j < 4; ++j) acc[i][j] = (f32x4){0.f, 0.f, 0.f, 0.f};

  const int fr = lane & 15;
  const int fk = (lane >> 4) * 8;
  const unsigned short* Alrd = Al + (wm * 64 + fr) * 32 + fk;
  const unsigned short* Blrd = Bl + (wn * 64 + fr) * 32 + fk;

  for (int k0 = 0; k0 < K; k0 += 32) {
    __syncthreads();
#pragma unroll
    for (int q = 0; q < 2; ++q) {
      gload_lds16(asrc[q] + k0, Al + (q * 256 + tid) * 8);
      gload_lds16(bsrc[q] + k0, Bl + (q * 256 + tid) * 8);
    }
    __syncthreads();
    bf16x8 af[4], bfr[4];
#pragma unroll
    for (int m = 0; m < 4; ++m) af[m]  = *(const bf16x8*)(Alrd + m * 16 * 32);
#pragma unroll
    for (int n = 0; n < 4; ++n) bfr[n] = *(const bf16x8*)(Blrd + n * 16 * 32);
#pragma unroll
    for (int m = 0; m < 4; ++m)
#pragma unroll
      for (int n = 0; n < 4; ++n)
        acc[m][n] = __builtin_amdgcn_mfma_f32_16x16x32_bf16(af[m], bfr[n], acc[m][n], 0, 0, 0);
  }
  const int r0 = (lane >> 4) * 4;
#pragma unroll
  for (int m = 0; m < 4; ++m) {
    int row = m0 + wm * 64 + m * 16 + r0;
#pragma unroll
    for (int n = 0; n < 4; ++n) {
      int col = wn * 64 + n * 16 + fr;
#pragma unroll
      for (int j = 0; j < 4; ++j)
        C[(long)(row + j) * 128 + col] = acc[m][n][j];
    }
  }
}

// ---------------- per-channel stats over x1 (bf16) ----------------
__global__ __launch_bounds__(256) void stats1(const unsigned short* __restrict__ x1,
                                              float* __restrict__ sum, float* __restrict__ ssq)
{
  const int tid = threadIdx.x;
  const int c0 = tid * 4;
  float s0=0,s1=0,s2=0,s3=0,q0=0,q1=0,q2=0,q3=0;
  for (int r = blockIdx.x; r < NPOS; r += gridDim.x) {
    uint2 v = *(const uint2*)(x1 + (long)r * 1024 + c0);
    float f0 = bf2f(v.x & 0xffffu), f1 = bf2f(v.x >> 16);
    float f2 = bf2f(v.y & 0xffffu), f3 = bf2f(v.y >> 16);
    s0 += f0; q0 += f0*f0;  s1 += f1; q1 += f1*f1;
    s2 += f2; q2 += f2*f2;  s3 += f3; q3 += f3*f3;
  }
  atomicAdd(&sum[c0+0], s0); atomicAdd(&ssq[c0+0], q0);
  atomicAdd(&sum[c0+1], s1); atomicAdd(&ssq[c0+1], q1);
  atomicAdd(&sum[c0+2], s2); atomicAdd(&ssq[c0+2], q2);
  atomicAdd(&sum[c0+3], s3); atomicAdd(&ssq[c0+3], q3);
}

__global__ void finalize_bn(const float* __restrict__ sum, const float* __restrict__ ssq,
                            const float* __restrict__ scale, const float* __restrict__ bias,
                            float* __restrict__ ab, int C, float invN)
{
  int c = blockIdx.x * blockDim.x + threadIdx.x;
  if (c >= C) return;
  float mean = sum[c] * invN;
  float var  = ssq[c] * invN - mean * mean;
  float a = scale[c] * rsqrtf(var + 1e-5f);
  ab[c] = a;
  ab[C + c] = bias[c] - mean * a;
}

// ---------------- relu(bn1(x1)) in place on bf16 x1 ----------------
__global__ __launch_bounds__(256) void bnrelu_x1(unsigned short* __restrict__ x1,
                                                 const float* __restrict__ ab)
{
  long base = ((long)blockIdx.x * 256 + threadIdx.x) * 8;
  int c0 = (int)(base & 1023);
  uint4 v = *(uint4*)(x1 + base);
  unsigned int w[4] = {v.x, v.y, v.z, v.w};
  unsigned int o[4];
#pragma unroll
  for (int j = 0; j < 4; ++j) {
    int c = c0 + j * 2;
    float lo = bf2f((unsigned short)(w[j] & 0xffffu));
    float hi = bf2f((unsigned short)(w[j] >> 16));
    lo = fmaxf(fmaf(lo, ab[c],     ab[1024 + c]),     0.f);
    hi = fmaxf(fmaf(hi, ab[c + 1], ab[1024 + c + 1]), 0.f);
    o[j] = pk2(lo, hi);
  }
  *(uint4*)(x1 + base) = make_uint4(o[0], o[1], o[2], o[3]);
}

// ---------------- stats over x2 (fp32, 128 ch) ----------------
__global__ __launch_bounds__(256) void stats2(const float* __restrict__ x2,
                                              float* __restrict__ sum, float* __restrict__ ssq)
{
  const int c = threadIdx.x & 127;
  const int g = threadIdx.x >> 7;
  float s = 0.f, q = 0.f;
  for (int r = blockIdx.x * 2 + g; r < NPOS; r += gridDim.x * 2) {
    float v = x2[(long)r * 128 + c];
    s += v; q += v * v;
  }
  atomicAdd(&sum[c], s); atomicAdd(&ssq[c], q);
}

// ---------------- apply bn2 + relu in place ----------------
__global__ __launch_bounds__(256) void apply_bn(float* __restrict__ x, const float* __restrict__ ab)
{
  int idx = (blockIdx.x * 256 + threadIdx.x) * 4;
  if (idx >= NPOS * 128) return;
  int c = idx & 127;
  float4 v = *(float4*)(x + idx);
  v.x = fmaxf(fmaf(v.x, ab[c+0], ab[128+c+0]), 0.f);
  v.y = fmaxf(fmaf(v.y, ab[c+1], ab[128+c+1]), 0.f);
  v.z = fmaxf(fmaf(v.z, ab[c+2], ab[128+c+2]), 0.f);
  v.w = fmaxf(fmaf(v.w, ab[c+3], ab[128+c+3]), 0.f);
  *(float4*)(x + idx) = v;
}

// ============================================================
// Fused message passing v2: weights resident in VGPRs.
// One block per batch, 512 threads = 8 waves = 4 n-groups x 2 k-halves.
// Per step: MFMA partials over own k-half -> LDS exchange of the
// complementary m-tile halves -> fused epilogue (x2 RMW + bf16 row
// into the next LDS row buffer). 2 barriers per step.
//   MT = # of 16-row m-tiles (7 for L=100, 3 for L=36)
//   MH = m-tiles epilogued by k-half 0
// ============================================================
#define MPROWS 120
#define MPBUF (MPROWS * 128)   // halfwords per row buffer
template<int MT, int MH>
__global__ __launch_bounds__(512) void mp_fused2(
    float* __restrict__ x2, const unsigned short* __restrict__ wt,
    const int L, const int posStride, const int rowStride,
    const int i0, const int di, const int nsteps)
{
  __shared__ unsigned short rowbuf[2 * MPBUF];       // 61440 B
  __shared__ float xch[MT * 8 * 16 * 17];            // partial-sum exchange (+1 pad)
  const int tid  = threadIdx.x;
  const int lane = tid & 63;
  const int wave = tid >> 6;        // 0..7
  const int ng   = wave & 3;        // n-group: cols ng*32 .. +31 (2 n-tiles)
  const int kh   = wave >> 2;       // k-half: k in [kh*576, kh*576+576)
  const int fr   = lane & 15;
  const int ks   = lane >> 4;       // 0..3
  float* xb = x2 + (long)blockIdx.x * 460800;

  // zero row buffers (halo rows stay zero forever)
  for (int i = tid; i < (2 * MPBUF) / 8; i += 512)
    *(uint4*)(rowbuf + i * 8) = make_uint4(0u, 0u, 0u, 0u);

  // B prologue: 36 x 16B per lane -> 144 VGPR, resident across all steps
  const unsigned short* wb = wt + (long)(ng * 32 + fr) * 1152 + kh * 576 + ks * 8;
  bf16x8 bfrag[2][18];
#pragma unroll
  for (int nt = 0; nt < 2; ++nt)
#pragma unroll
    for (int kk = 0; kk < 18; ++kk)
      bfrag[nt][kk] = *(const bf16x8*)(wb + nt * 16 * 1152 + kk * 32);

  __syncthreads();
  // load row i0 -> buf0 (bf16, swizzled); row i0 is never modified
  for (int e = tid * 4; e < L * 128; e += 2048) {
    int w = e >> 7, c = e & 127;
    float4 v = *(const float4*)(xb + (long)i0 * rowStride + (long)w * posStride + c);
    int br = w + 4;
    int byte = (br * 256 + c * 2) ^ ((br & 7) << 4);
    *(uint2*)((char*)rowbuf + byte) = make_uint2(pk2(v.x, v.y), pk2(v.z, v.w));
  }
  __syncthreads();

  for (int s = 1; s <= nsteps; ++s) {
    const char* curb = (const char*)rowbuf + (((s & 1) ^ 1) * MPBUF) * 2;
    char* nxtb = (char*)rowbuf + ((s & 1) * MPBUF) * 2;
    const int i = i0 + s * di;

    f32x4 acc[MT][2];
#pragma unroll
    for (int mt = 0; mt < MT; ++mt) {
      acc[mt][0] = (f32x4){0.f, 0.f, 0.f, 0.f};
      acc[mt][1] = (f32x4){0.f, 0.f, 0.f, 0.f};
    }

#pragma unroll
    for (int kk = 0; kk < 18; ++kk) {
      const int k0 = kh * 576 + kk * 32;
      const int tap = k0 >> 7;
      const int colb = ((k0 & 127) + ks * 8) * 2;
      const int br0 = fr + tap;
      const int byte0 = (br0 * 256 + colb) ^ ((br0 & 7) << 4);  // (br+16)&7 == br&7
#pragma unroll
      for (int mt = 0; mt < MT; ++mt) {
        bf16x8 af = *(const bf16x8*)(curb + byte0 + mt * 4096);
        acc[mt][0] = __builtin_amdgcn_mfma_f32_16x16x32_bf16(af, bfrag[0][kk], acc[mt][0], 0, 0, 0);
        acc[mt][1] = __builtin_amdgcn_mfma_f32_16x16x32_bf16(af, bfrag[1][kk], acc[mt][1], 0, 0, 0);
      }
    }

    // write partials for the m-tiles the OTHER k-half will epilogue
#pragma unroll
    for (int mt = 0; mt < MT; ++mt) {
      const bool mine = (kh == 0) ? (mt >= MH) : (mt < MH);
      if (mine) {
#pragma unroll
        for (int nt = 0; nt < 2; ++nt) {
          float* dst = &xch[((mt * 8 + ng * 2 + nt) * 16) * 17];
#pragma unroll
          for (int j = 0; j < 4; ++j)
            dst[(ks * 4 + j) * 17 + fr] = acc[mt][nt][j];
        }
      }
    }
    __syncthreads();
    // epilogue: own acc + xch -> relu -> x2 RMW + next row into LDS
#pragma unroll
    for (int mt = 0; mt < MT; ++mt) {
      const bool epi = (kh == 0) ? (mt < MH) : (mt >= MH);
      if (epi) {
#pragma unroll
        for (int nt = 0; nt < 2; ++nt) {
          const int col = ng * 32 + nt * 16 + fr;
          const float* src = &xch[((mt * 8 + ng * 2 + nt) * 16) * 17];
#pragma unroll
          for (int j = 0; j < 4; ++j) {
            const int m = mt * 16 + ks * 4 + j;
            if (m < L) {
              float v = acc[mt][nt][j] + src[(ks * 4 + j) * 17 + fr];
              long off = (long)i * rowStride + (long)m * posStride + col;
              float nv = xb[off] + fmaxf(v, 0.f);
              xb[off] = nv;
              int br = m + 4;
              int byte = (br * 256 + col * 2) ^ ((br & 7) << 4);
              *(unsigned short*)(nxtb + byte) = f2bf(nv);
            }
          }
        }
      }
    }
    __syncthreads();
  }
}

// ---------------- segmentation head: 128 -> 5 + bias ----------------
__global__ __launch_bounds__(256) void seg_head(
    const float* __restrict__ xn, const float* __restrict__ w_seg,
    const float* __restrict__ b_seg, float* __restrict__ logits)
{
  __shared__ float ws[128 * 5];
  __shared__ float xs[32][129];
  const int tid = threadIdx.x;
  for (int i = tid; i < 640; i += 256) ws[i] = w_seg[i];
  const int pos0 = blockIdx.x * 32;
  for (int idx = tid; idx < 32 * 32; idx += 256) {
    int r = idx >> 5, q = idx & 31;
    float4 v = *(const float4*)(xn + (long)(pos0 + r) * 128 + q * 4);
    xs[r][q*4+0]=v.x; xs[r][q*4+1]=v.y; xs[r][q*4+2]=v.z; xs[r][q*4+3]=v.w;
  }
  __syncthreads();
  int r = tid >> 3, f = tid & 7;
  if (f < 5) {
    float acc = b_seg[f];
#pragma unroll 4
    for (int ci = 0; ci < 128; ++ci) acc = fmaf(xs[r][ci], ws[ci*5 + f], acc);
    logits[(long)(pos0 + r) * 5 + f] = acc;
  }
}

// ---------------- softmax + 2x2 mean pool ----------------
__global__ __launch_bounds__(256) void softpool(const float* __restrict__ logits, float* __restrict__ p)
{
  int idx = blockIdx.x * 256 + threadIdx.x;
  if (idx >= 16 * 18 * 50) return;
  int ww = idx % 50, hh = (idx / 50) % 18, b = idx / 900;
  float avg[5] = {0,0,0,0,0};
#pragma unroll
  for (int i = 0; i < 2; ++i)
#pragma unroll
    for (int j = 0; j < 2; ++j) {
      const float* L = logits + ((long)((b*36 + hh*2 + i) * 100) + ww*2 + j) * 5;
      float l0=L[0], l1=L[1], l2=L[2], l3=L[3], l4=L[4];
      float m = fmaxf(fmaxf(fmaxf(l0,l1), fmaxf(l2,l3)), l4);
      float e0=expf(l0-m), e1=expf(l1-m), e2=expf(l2-m), e3=expf(l3-m), e4=expf(l4-m);
      float inv = 1.f / (e0+e1+e2+e3+e4);
      avg[0] += e0*inv; avg[1] += e1*inv; avg[2] += e2*inv; avg[3] += e3*inv; avg[4] += e4*inv;
    }
  float* dst = p + (long)b * 4500 + (hh * 50 + ww) * 5;
#pragma unroll
  for (int f = 0; f < 5; ++f) dst[f] = avg[f] * 0.25f;
}

// ---------------- fc1 ----------------
__global__ __launch_bounds__(128) void fc1_kernel(
    const float* __restrict__ p, const float* __restrict__ w,
    const float* __restrict__ bias, float* __restrict__ z)
{
  __shared__ float ps[4500];
  const int b = blockIdx.x, tid = threadIdx.x;
  for (int i = tid; i < 4500; i += 128) ps[i] = p[(long)b * 4500 + i];
  __syncthreads();
  float acc = bias[tid];
#pragma unroll 4
  for (int m = 0; m < 4500; ++m) acc = fmaf(ps[m], w[(long)m * 128 + tid], acc);
  z[b * 128 + tid] = fmaxf(acc, 0.f);
}

// ---------------- fc2 ----------------
__global__ void fc2_kernel(const float* __restrict__ z, const float* __restrict__ w,
                           const float* __restrict__ bias, float* __restrict__ out)
{
  int t = threadIdx.x;
  if (t >= 64) return;
  int b = t >> 2, j = t & 3;
  float acc = bias[j];
#pragma unroll 4
  for (int n = 0; n < 128; ++n) acc = fmaf(z[b*128 + n], w[n*4 + j], acc);
  out[b*4 + j] = acc;
}

// ---------------- 8x bilinear resize ----------------
__global__ __launch_bounds__(256) void resize_bilinear(
    const float* __restrict__ logits, float* __restrict__ out)
{
  int idx = blockIdx.x * 256 + threadIdx.x;
  if (idx >= 18432000) return;
  int f = idx % 5;
  int t = idx / 5;
  int ow = t % 800; t /= 800;
  int oh = t % 288;
  int b = t / 288;
  float sh = (oh + 0.5f) * 0.125f - 0.5f;
  float sw = (ow + 0.5f) * 0.125f - 0.5f;
  int h0 = (int)floorf(sh); float fh = sh - (float)h0;
  int w0 = (int)floorf(sw); float fw = sw - (float)w0;
  int h1 = min(h0 + 1, 35); h0 = max(h0, 0);
  int w1 = min(w0 + 1, 99); w0 = max(w0, 0);
  const float* Lb = logits + (long)b * 36 * 100 * 5 + f;
  float v00 = Lb[(h0*100 + w0)*5], v01 = Lb[(h0*100 + w1)*5];
  float v10 = Lb[(h1*100 + w0)*5], v11 = Lb[(h1*100 + w1)*5];
  float v = (1.f-fh) * ((1.f-fw)*v00 + fw*v01) + fh * ((1.f-fw)*v10 + fw*v11);
  out[idx] = v;
}

// ============================================================
extern "C" void kernel_launch(void* const* d_in, const int* in_sizes, int n_in,
                              void* d_out, int out_size, void* d_ws, size_t ws_size,
                              hipStream_t stream)
{
  (void)in_sizes; (void)n_in; (void)out_size; (void)ws_size;
  const float* features = (const float*)d_in[0];
  const float* w_conv1  = (const float*)d_in[1];
  const float* bn1_s    = (const float*)d_in[2];
  const float* bn1_b    = (const float*)d_in[3];
  const float* w_conv2  = (const float*)d_in[4];
  const float* bn2_s    = (const float*)d_in[5];
  const float* bn2_b    = (const float*)d_in[6];
  const float* w_vf     = (const float*)d_in[7];
  const float* w_vr     = (const float*)d_in[8];
  const float* w_hf     = (const float*)d_in[9];
  const float* w_hr     = (const float*)d_in[10];
  const float* w_seg    = (const float*)d_in[11];
  const float* b_seg    = (const float*)d_in[12];
  const float* w_fc1    = (const float*)d_in[13];
  const float* b_fc1    = (const float*)d_in[14];
  const float* w_fc2    = (const float*)d_in[15];
  const float* b_fc2    = (const float*)d_in[16];

  char* ws = (char*)d_ws;
  unsigned short* x1  = (unsigned short*)ws;                // 117,964,800 B bf16
  unsigned short* w1t = (unsigned short*)(ws + 117964800);  // overlaps x2 (dead until conv2)
  float* x2     = (float*)(ws + 117964800);                 // 29,491,200 B f32
  float* logits = (float*)(ws + 147456000);                 // 1,152,000 B
  // wtmp overlaps logits+pbuf: dead until after MP (seg_head writes logits later)
  unsigned short* wtmp = (unsigned short*)(ws + 147456000); // 1,179,648 B (4 x 147456 hw)
  float* pbuf   = (float*)(ws + 148608000);                 // 288,000 B
  float* zbuf   = (float*)(ws + 148896000);                 // 8,192 B
  float* stats  = (float*)(ws + 148904192);                 // 9,216 B
  float* ab1    = (float*)(ws + 148913408);                 // 8,192 B
  float* ab2    = (float*)(ws + 148921600);                 // 1,024 B
  unsigned short* w2t = (unsigned short*)(ws + 148922624);  // 262,144 B
  float* outf   = (float*)d_out;

  hipMemsetAsync(stats, 0, 2304 * sizeof(float), stream);
  convert_w1t<<<2304, 256, 0, stream>>>(w_conv1, w1t);
  convert_w2t<<<64, 256, 0, stream>>>(w_conv2, w2t);
  convert_wmp<<<72, 256, 0, stream>>>(w_vf, wtmp + 0 * 147456);
  convert_wmp<<<72, 256, 0, stream>>>(w_vr, wtmp + 1 * 147456);
  convert_wmp<<<72, 256, 0, stream>>>(w_hf, wtmp + 2 * 147456);
  convert_wmp<<<72, 256, 0, stream>>>(w_hr, wtmp + 3 * 147456);

  conv1_mfma<<<dim3(8, 450), 256, 0, stream>>>(features, w1t, x1);
  stats1<<<512, 256, 0, stream>>>(x1, stats, stats + 1024);
  finalize_bn<<<4, 256, 0, stream>>>(stats, stats + 1024, bn1_s, bn1_b, ab1, 1024, 1.0f/57600.0f);
  bnrelu_x1<<<28800, 256, 0, stream>>>(x1, ab1);
  gemm_mfma_128<<<450, 256, 0, stream>>>(x1, w2t, x2, 1024);
  stats2<<<256, 256, 0, stream>>>(x2, stats + 2048, stats + 2176);
  finalize_bn<<<1, 128, 0, stream>>>(stats + 2048, stats + 2176, bn2_s, bn2_b, ab2, 128, 1.0f/57600.0f);
  apply_bn<<<7200, 256, 0, stream>>>(x2, ab2);

  // fused message passing: 4 launches, weights in VGPRs
  mp_fused2<7,3><<<NB, 512, 0, stream>>>(x2, wtmp + 0 * 147456, 100, 128,   12800, 0,  +1, 35);
  mp_fused2<7,3><<<NB, 512, 0, stream>>>(x2, wtmp + 1 * 147456, 100, 128,   12800, 35, -1, 35);
  mp_fused2<3,1><<<NB, 512, 0, stream>>>(x2, wtmp + 2 * 147456, 36,  12800, 128,   0,  +1, 99);
  mp_fused2<3,1><<<NB, 512, 0, stream>>>(x2, wtmp + 3 * 147456, 36,  12800, 128,   99, -1, 99);

  seg_head<<<1800, 256, 0, stream>>>(x2, w_seg, b_seg, logits);
  softpool<<<57, 256, 0, stream>>>(logits, pbuf);
  fc1_kernel<<<16, 128, 0, stream>>>(pbuf, w_fc1, b_fc1, zbuf);
  fc2_kernel<<<1, 64, 0, stream>>>(zbuf, w_fc2, b_fc2, outf + 18432000);
  resize_bilinear<<<72000, 256, 0, stream>>>(logits, outf);
}

// Round 5
// 3818.995 us; speedup vs baseline: 5.7100x; 1.0767x over previous
//
#include <hip/hip_runtime.h>
#include <hip/hip_bf16.h>

#define NB 16
#define NPOS 57600

typedef short bf16x8 __attribute__((ext_vector_type(8)));
typedef float f32x4 __attribute__((ext_vector_type(4)));

__device__ __forceinline__ float bf2f(unsigned short u) {
  union { unsigned int i; float f; } c; c.i = ((unsigned int)u) << 16; return c.f;
}
// round-to-nearest-even f32 -> bf16 bits
__device__ __forceinline__ unsigned short f2bf(float f) {
  union { float f; unsigned int i; } c; c.f = f;
  unsigned int x = c.i;
  x += 0x7fffu + ((x >> 16) & 1u);
  return (unsigned short)(x >> 16);
}
__device__ __forceinline__ unsigned int pk2(float lo, float hi) {
  return (unsigned int)f2bf(lo) | ((unsigned int)f2bf(hi) << 16);
}

__device__ __forceinline__ void gload_lds16(const void* g, void* l) {
  __builtin_amdgcn_global_load_lds(
      (const __attribute__((address_space(1))) unsigned int*)(g),
      (__attribute__((address_space(3))) unsigned int*)(l), 16, 0, 0);
}

// ---------------- weight conversions (one-time, tiny) ----------------
// w1 (4608,1024) f32 -> w1t (1024,4608) bf16
__global__ __launch_bounds__(256) void convert_w1t(const float* __restrict__ w,
                                                   unsigned short* __restrict__ wt)
{
  int idx = blockIdx.x * 256 + threadIdx.x;     // 589824 jobs
  int n = idx & 1023;
  int k0 = (idx >> 10) * 8;
  unsigned int o[4];
#pragma unroll
  for (int j = 0; j < 4; ++j) {
    float lo = w[(long)(k0 + 2*j)     * 1024 + n];
    float hi = w[(long)(k0 + 2*j + 1) * 1024 + n];
    o[j] = pk2(lo, hi);
  }
  *(uint4*)(wt + (long)n * 4608 + k0) = make_uint4(o[0], o[1], o[2], o[3]);
}

// w2 (1024,128) f32 -> w2t (128,1024) bf16
__global__ __launch_bounds__(256) void convert_w2t(const float* __restrict__ w,
                                                   unsigned short* __restrict__ wt)
{
  int idx = blockIdx.x * 256 + threadIdx.x;     // 16384 jobs
  int n = idx & 127;
  int k0 = (idx >> 7) * 8;
  unsigned int o[4];
#pragma unroll
  for (int j = 0; j < 4; ++j) {
    float lo = w[(long)(k0 + 2*j)     * 128 + n];
    float hi = w[(long)(k0 + 2*j + 1) * 128 + n];
    o[j] = pk2(lo, hi);
  }
  *(uint4*)(wt + (long)n * 1024 + k0) = make_uint4(o[0], o[1], o[2], o[3]);
}

// w_mp (9,128,128)[tap][ci][co] f32 -> wt (128,1152)[co][tap*128+ci] bf16
__global__ __launch_bounds__(256) void convert_wmp(const float* __restrict__ w,
                                                   unsigned short* __restrict__ wt)
{
  int idx = blockIdx.x * 256 + threadIdx.x;     // 18432 jobs
  if (idx >= 18432) return;
  int co = idx & 127;
  int kg = idx >> 7;                            // 0..143
  int k0 = kg * 8;
  int tap = k0 >> 7, ci0 = k0 & 127;
  const float* src = w + (long)tap * 16384 + (long)ci0 * 128 + co;
  unsigned int o[4];
#pragma unroll
  for (int j = 0; j < 4; ++j)
    o[j] = pk2(src[(2*j) * 128], src[(2*j+1) * 128]);
  *(uint4*)(wt + (long)co * 1152 + k0) = make_uint4(o[0], o[1], o[2], o[3]);
}

// ---------------- pad+convert features: f32 (16,36,100,512) -> bf16 (16,44,108,512) ----------------
__global__ __launch_bounds__(256) void pad_features(const float* __restrict__ src,
                                                    unsigned short* __restrict__ dst)
{
  long idx = (long)blockIdx.x * 256 + threadIdx.x;   // 4,866,048 jobs (8 ch each)
  if (idx >= 16L * 44 * 108 * 64) return;
  int c8 = (int)(idx & 63);
  long pos = idx >> 6;
  int wp = (int)(pos % 108); pos /= 108;
  int hp = (int)(pos % 44);
  int b  = (int)(pos / 44);
  uint4 o = make_uint4(0u, 0u, 0u, 0u);
  if (hp >= 4 && hp < 40 && wp >= 4 && wp < 104) {
    const float* s = src + (((long)b * 36 + (hp - 4)) * 100 + (wp - 4)) * 512 + c8 * 8;
    float4 v0 = *(const float4*)s;
    float4 v1 = *(const float4*)(s + 4);
    o = make_uint4(pk2(v0.x, v0.y), pk2(v0.z, v0.w), pk2(v1.x, v1.y), pk2(v1.z, v1.w));
  }
  *(uint4*)(dst + (((long)b * 44 + hp) * 108 + wp) * 512 + c8 * 8) = o;
}

// ============================================================
// conv1 v2: padded bf16 input, pure global_load_lds staging,
// XCD-chunked swizzle. GEMM M=57600, K=4608, N=1024.
// ============================================================
__global__ __launch_bounds__(256) void conv1_mfma2(
    const unsigned short* __restrict__ inp,  // (16,44,108,512) bf16 padded
    const unsigned short* __restrict__ w1t,  // (1024,4608) bf16 [n][k]
    unsigned short* __restrict__ x1)         // (57600,1024) bf16
{
  __shared__ unsigned short Al[128 * 32];
  __shared__ unsigned short Bl[128 * 32];
  const int tid  = threadIdx.x;
  const int lane = tid & 63;
  const int wave = tid >> 6;
  const int wm = wave >> 1, wn = wave & 1;
  // bijective XCD-chunked swizzle: 3600 blocks = 8 chunks x 450
  const int bid  = blockIdx.x;
  const int nbid = (bid & 7) * 450 + (bid >> 3);
  const int n0 = (nbid & 7) * 128;      // n fastest: 8 n-blocks share A-panel on same XCD
  const int m0 = (nbid >> 3) * 128;

  long aoff[2];
  const unsigned short* bsrc[2];
#pragma unroll
  for (int q = 0; q < 2; ++q) {
    int e = q * 256 + tid;
    int row = e >> 2;
    int kl  = (e & 3) * 8;
    int m = m0 + row;
    int w = m % 100, h = (m / 100) % 36, b = m / 3600;
    aoff[q] = (((long)b * 44 + h + 4) * 108 + (w + 4)) * 512 + kl;
    bsrc[q] = w1t + (long)(n0 + row) * 4608 + kl;
  }

  f32x4 acc[4][4];
#pragma unroll
  for (int i = 0; i < 4; ++i)
#pragma unroll
    for (int j = 0; j < 4; ++j) acc[i][j] = (f32x4){0.f, 0.f, 0.f, 0.f};

  const int fr = lane & 15;
  const int fk = (lane >> 4) * 8;
  const unsigned short* Alrd = Al + (wm * 64 + fr) * 32 + fk;
  const unsigned short* Blrd = Bl + (wn * 64 + fr) * 32 + fk;

  for (int k0 = 0; k0 < 4608; k0 += 32) {
    const int tap = k0 >> 9;
    const int ci0 = k0 & 511;
    const int dh = (tap / 3) * 4 - 4, dw = (tap % 3) * 4 - 4;
    const long delta = (long)(dh * 108 + dw) * 512 + ci0;
    __syncthreads();
#pragma unroll
    for (int q = 0; q < 2; ++q) {
      gload_lds16(inp + aoff[q] + delta, Al + (q * 256 + tid) * 8);
      gload_lds16(bsrc[q] + k0,          Bl + (q * 256 + tid) * 8);
    }
    __syncthreads();
    bf16x8 af[4], bfr[4];
#pragma unroll
    for (int m = 0; m < 4; ++m) af[m]  = *(const bf16x8*)(Alrd + m * 16 * 32);
#pragma unroll
    for (int n = 0; n < 4; ++n) bfr[n] = *(const bf16x8*)(Blrd + n * 16 * 32);
#pragma unroll
    for (int m = 0; m < 4; ++m)
#pragma unroll
      for (int n = 0; n < 4; ++n)
        acc[m][n] = __builtin_amdgcn_mfma_f32_16x16x32_bf16(af[m], bfr[n], acc[m][n], 0, 0, 0);
  }
  const int r0 = (lane >> 4) * 4;
#pragma unroll
  for (int m = 0; m < 4; ++m) {
    int row = m0 + wm * 64 + m * 16 + r0;
#pragma unroll
    for (int n = 0; n < 4; ++n) {
      int col = n0 + wn * 64 + n * 16 + fr;
#pragma unroll
      for (int j = 0; j < 4; ++j)
        x1[(long)(row + j) * 1024 + col] = f2bf(acc[m][n][j]);
    }
  }
}

// ============================================================
// conv1 v1 (fallback when ws too small for padded features)
// ============================================================
__global__ __launch_bounds__(256) void conv1_mfma(
    const float* __restrict__ in,
    const unsigned short* __restrict__ w1t,
    unsigned short* __restrict__ x1)
{
  __shared__ unsigned short Al[128 * 32];
  __shared__ unsigned short Bl[128 * 32];
  const int tid  = threadIdx.x;
  const int lane = tid & 63;
  const int wave = tid >> 6;
  const int wm = wave >> 1, wn = wave & 1;
  const int m0 = blockIdx.y * 128;
  const int n0 = blockIdx.x * 128;

  int akl[2], ab_[2], ah_[2], aw_[2];
  const unsigned short* bsrc[2];
#pragma unroll
  for (int q = 0; q < 2; ++q) {
    int e = q * 256 + tid;
    int row = e >> 2;
    akl[q]  = (e & 3) * 8;
    int m = m0 + row;
    aw_[q] = m % 100;
    ah_[q] = (m / 100) % 36;
    ab_[q] = m / 3600;
    bsrc[q] = w1t + (long)(n0 + row) * 4608 + akl[q];
  }

  f32x4 acc[4][4];
#pragma unroll
  for (int i = 0; i < 4; ++i)
#pragma unroll
    for (int j = 0; j < 4; ++j) acc[i][j] = (f32x4){0.f, 0.f, 0.f, 0.f};

  const int fr = lane & 15;
  const int fk = (lane >> 4) * 8;
  const unsigned short* Alrd = Al + (wm * 64 + fr) * 32 + fk;
  const unsigned short* Blrd = Bl + (wn * 64 + fr) * 32 + fk;

  for (int k0 = 0; k0 < 4608; k0 += 32) {
    const int tap = k0 >> 9;
    const int ci0 = k0 & 511;
    const int dh = (tap / 3) * 4 - 4, dw = (tap % 3) * 4 - 4;
    unsigned int apk[2][4];
#pragma unroll
    for (int q = 0; q < 2; ++q) {
      int ih = ah_[q] + dh, iw = aw_[q] + dw;
      if ((unsigned)ih < 36u && (unsigned)iw < 100u) {
        const float* s = in + ((((long)ab_[q] * 36 + ih) * 100 + iw) << 9) + ci0 + akl[q];
        float4 v0 = *(const float4*)s;
        float4 v1 = *(const float4*)(s + 4);
        apk[q][0] = pk2(v0.x, v0.y); apk[q][1] = pk2(v0.z, v0.w);
        apk[q][2] = pk2(v1.x, v1.y); apk[q][3] = pk2(v1.z, v1.w);
      } else {
        apk[q][0] = apk[q][1] = apk[q][2] = apk[q][3] = 0u;
      }
    }
    __syncthreads();
#pragma unroll
    for (int q = 0; q < 2; ++q) {
      *(uint4*)(Al + (q * 256 + tid) * 8) = *(uint4*)apk[q];
      gload_lds16(bsrc[q] + k0, Bl + (q * 256 + tid) * 8);
    }
    __syncthreads();
    bf16x8 af[4], bfr[4];
#pragma unroll
    for (int m = 0; m < 4; ++m) af[m]  = *(const bf16x8*)(Alrd + m * 16 * 32);
#pragma unroll
    for (int n = 0; n < 4; ++n) bfr[n] = *(const bf16x8*)(Blrd + n * 16 * 32);
#pragma unroll
    for (int m = 0; m < 4; ++m)
#pragma unroll
      for (int n = 0; n < 4; ++n)
        acc[m][n] = __builtin_amdgcn_mfma_f32_16x16x32_bf16(af[m], bfr[n], acc[m][n], 0, 0, 0);
  }
  const int r0 = (lane >> 4) * 4;
#pragma unroll
  for (int m = 0; m < 4; ++m) {
    int row = m0 + wm * 64 + m * 16 + r0;
#pragma unroll
    for (int n = 0; n < 4; ++n) {
      int col = n0 + wn * 64 + n * 16 + fr;
#pragma unroll
      for (int j = 0; j < 4; ++j)
        x1[(long)(row + j) * 1024 + col] = f2bf(acc[m][n][j]);
    }
  }
}

// ============================================================
// conv2: bf16 GEMM A(M,1024) x Bt(128,1024) -> C(M,128) f32
// ============================================================
__global__ __launch_bounds__(256) void gemm_mfma_128(
    const unsigned short* __restrict__ A,
    const unsigned short* __restrict__ Bt,
    float* __restrict__ C, int K)
{
  __shared__ unsigned short Al[128 * 32];
  __shared__ unsigned short Bl[128 * 32];
  const int tid  = threadIdx.x;
  const int lane = tid & 63;
  const int wave = tid >> 6;
  const int wm = wave >> 1, wn = wave & 1;
  const int m0 = blockIdx.x * 128;

  const unsigned short* asrc[2];
  const unsigned short* bsrc[2];
#pragma unroll
  for (int q = 0; q < 2; ++q) {
    int e = q * 256 + tid;
    int row = e >> 2;
    int kl  = (e & 3) * 8;
    asrc[q] = A  + (long)(m0 + row) * K + kl;
    bsrc[q] = Bt + (long)row * K + kl;
  }

  f32x4 acc[4][4];
#pragma unroll
  for (int i = 0; i < 4; ++i)
#pragma unroll
    for (int j = 0; j < 4; ++j) acc[i][j] = (f32x4){0.f, 0.f, 0.f, 0.f};

  const int fr = lane & 15;
  const int fk = (lane >> 4) * 8;
  const unsigned short* Alrd = Al + (wm * 64 + fr) * 32 + fk;
  const unsigned short* Blrd = Bl + (wn * 64 + fr) * 32 + fk;

  for (int k0 = 0; k0 < K; k0 += 32) {
    __syncthreads();
#pragma unroll
    for (int q = 0; q < 2; ++q) {
      gload_lds16(asrc[q] + k0, Al + (q * 256 + tid) * 8);
      gload_lds16(bsrc[q] + k0, Bl + (q * 256 + tid) * 8);
    }
    __syncthreads();
    bf16x8 af[4], bfr[4];
#pragma unroll
    for (int m = 0; m < 4; ++m) af[m]  = *(const bf16x8*)(Alrd + m * 16 * 32);
#pragma unroll
    for (int n = 0; n < 4; ++n) bfr[n] = *(const bf16x8*)(Blrd + n * 16 * 32);
#pragma unroll
    for (int m = 0; m < 4; ++m)
#pragma unroll
      for (int n = 0; n < 4; ++n)
        acc[m][n] = __builtin_amdgcn_mfma_f32_16x16x32_bf16(af[m], bfr[n], acc[m][n], 0, 0, 0);
  }
  const int r0 = (lane >> 4) * 4;
#pragma unroll
  for (int m = 0; m < 4; ++m) {
    int row = m0 + wm * 64 + m * 16 + r0;
#pragma unroll
    for (int n = 0; n < 4; ++n) {
      int col = wn * 64 + n * 16 + fr;
#pragma unroll
      for (int j = 0; j < 4; ++j)
        C[(long)(row + j) * 128 + col] = acc[m][n][j];
    }
  }
}

// ---------------- per-channel stats over x1 (bf16) ----------------
__global__ __launch_bounds__(256) void stats1(const unsigned short* __restrict__ x1,
                                              float* __restrict__ sum, float* __restrict__ ssq)
{
  const int tid = threadIdx.x;
  const int c0 = tid * 4;
  float s0=0,s1=0,s2=0,s3=0,q0=0,q1=0,q2=0,q3=0;
  for (int r = blockIdx.x; r < NPOS; r += gridDim.x) {
    uint2 v = *(const uint2*)(x1 + (long)r * 1024 + c0);
    float f0 = bf2f(v.x & 0xffffu), f1 = bf2f(v.x >> 16);
    float f2 = bf2f(v.y & 0xffffu), f3 = bf2f(v.y >> 16);
    s0 += f0; q0 += f0*f0;  s1 += f1; q1 += f1*f1;
    s2 += f2; q2 += f2*f2;  s3 += f3; q3 += f3*f3;
  }
  atomicAdd(&sum[c0+0], s0); atomicAdd(&ssq[c0+0], q0);
  atomicAdd(&sum[c0+1], s1); atomicAdd(&ssq[c0+1], q1);
  atomicAdd(&sum[c0+2], s2); atomicAdd(&ssq[c0+2], q2);
  atomicAdd(&sum[c0+3], s3); atomicAdd(&ssq[c0+3], q3);
}

__global__ void finalize_bn(const float* __restrict__ sum, const float* __restrict__ ssq,
                            const float* __restrict__ scale, const float* __restrict__ bias,
                            float* __restrict__ ab, int C, float invN)
{
  int c = blockIdx.x * blockDim.x + threadIdx.x;
  if (c >= C) return;
  float mean = sum[c] * invN;
  float var  = ssq[c] * invN - mean * mean;
  float a = scale[c] * rsqrtf(var + 1e-5f);
  ab[c] = a;
  ab[C + c] = bias[c] - mean * a;
}

// ---------------- relu(bn1(x1)) in place on bf16 x1 ----------------
__global__ __launch_bounds__(256) void bnrelu_x1(unsigned short* __restrict__ x1,
                                                 const float* __restrict__ ab)
{
  long base = ((long)blockIdx.x * 256 + threadIdx.x) * 8;
  int c0 = (int)(base & 1023);
  uint4 v = *(uint4*)(x1 + base);
  unsigned int w[4] = {v.x, v.y, v.z, v.w};
  unsigned int o[4];
#pragma unroll
  for (int j = 0; j < 4; ++j) {
    int c = c0 + j * 2;
    float lo = bf2f((unsigned short)(w[j] & 0xffffu));
    float hi = bf2f((unsigned short)(w[j] >> 16));
    lo = fmaxf(fmaf(lo, ab[c],     ab[1024 + c]),     0.f);
    hi = fmaxf(fmaf(hi, ab[c + 1], ab[1024 + c + 1]), 0.f);
    o[j] = pk2(lo, hi);
  }
  *(uint4*)(x1 + base) = make_uint4(o[0], o[1], o[2], o[3]);
}

// ---------------- stats over x2 (fp32, 128 ch) ----------------
__global__ __launch_bounds__(256) void stats2(const float* __restrict__ x2,
                                              float* __restrict__ sum, float* __restrict__ ssq)
{
  const int c = threadIdx.x & 127;
  const int g = threadIdx.x >> 7;
  float s = 0.f, q = 0.f;
  for (int r = blockIdx.x * 2 + g; r < NPOS; r += gridDim.x * 2) {
    float v = x2[(long)r * 128 + c];
    s += v; q += v * v;
  }
  atomicAdd(&sum[c], s); atomicAdd(&ssq[c], q);
}

// ---------------- apply bn2 + relu in place ----------------
__global__ __launch_bounds__(256) void apply_bn(float* __restrict__ x, const float* __restrict__ ab)
{
  int idx = (blockIdx.x * 256 + threadIdx.x) * 4;
  if (idx >= NPOS * 128) return;
  int c = idx & 127;
  float4 v = *(float4*)(x + idx);
  v.x = fmaxf(fmaf(v.x, ab[c+0], ab[128+c+0]), 0.f);
  v.y = fmaxf(fmaf(v.y, ab[c+1], ab[128+c+1]), 0.f);
  v.z = fmaxf(fmaf(v.z, ab[c+2], ab[128+c+2]), 0.f);
  v.w = fmaxf(fmaf(v.w, ab[c+3], ab[128+c+3]), 0.f);
  *(float4*)(x + idx) = v;
}

// ============================================================
// Fused message passing v3: weights in VGPRs + x2-row prefetch
// (epilogue is store-only; the old global RMW latency chain is
// hoisted ahead of the k-loop and hidden under the MFMAs).
// ============================================================
#define MPROWS 120
#define MPBUF (MPROWS * 128)   // halfwords per row buffer
template<int MT, int MH>
__global__ __launch_bounds__(512) void mp_fused2(
    float* __restrict__ x2, const unsigned short* __restrict__ wt,
    const int L, const int posStride, const int rowStride,
    const int i0, const int di, const int nsteps)
{
  constexpr int MTE = (MT - MH > MH) ? (MT - MH) : MH;
  __shared__ unsigned short rowbuf[2 * MPBUF];       // 61440 B
  __shared__ float xch[MT * 8 * 16 * 17];            // partial-sum exchange (+1 pad)
  const int tid  = threadIdx.x;
  const int lane = tid & 63;
  const int wave = tid >> 6;        // 0..7
  const int ng   = wave & 3;        // n-group: cols ng*32 .. +31 (2 n-tiles)
  const int kh   = wave >> 2;       // k-half: k in [kh*576, kh*576+576)
  const int fr   = lane & 15;
  const int ks   = lane >> 4;       // 0..3
  float* xb = x2 + (long)blockIdx.x * 460800;

  // zero row buffers (halo rows stay zero forever)
  for (int i = tid; i < (2 * MPBUF) / 8; i += 512)
    *(uint4*)(rowbuf + i * 8) = make_uint4(0u, 0u, 0u, 0u);

  // B prologue: 36 x 16B per lane -> 144 VGPR, resident across all steps
  const unsigned short* wb = wt + (long)(ng * 32 + fr) * 1152 + kh * 576 + ks * 8;
  bf16x8 bfrag[2][18];
#pragma unroll
  for (int nt = 0; nt < 2; ++nt)
#pragma unroll
    for (int kk = 0; kk < 18; ++kk)
      bfrag[nt][kk] = *(const bf16x8*)(wb + nt * 16 * 1152 + kk * 32);

  __syncthreads();
  // load row i0 -> buf0 (bf16, swizzled); row i0 is never modified
  for (int e = tid * 4; e < L * 128; e += 2048) {
    int w = e >> 7, c = e & 127;
    float4 v = *(const float4*)(xb + (long)i0 * rowStride + (long)w * posStride + c);
    int br = w + 4;
    int byte = (br * 256 + c * 2) ^ ((br & 7) << 4);
    *(uint2*)((char*)rowbuf + byte) = make_uint2(pk2(v.x, v.y), pk2(v.z, v.w));
  }
  __syncthreads();

#define MP_PF(mt, pi)                                                          \
  _Pragma("unroll")                                                            \
  for (int nt = 0; nt < 2; ++nt) {                                             \
    _Pragma("unroll")                                                          \
    for (int j = 0; j < 4; ++j) {                                              \
      int m = (mt) * 16 + ks * 4 + j;                                          \
      pf[pi][nt][j] = (m < L)                                                  \
        ? xb[(long)i * rowStride + (long)m * posStride + ng * 32 + nt * 16 + fr] \
        : 0.f;                                                                 \
    }                                                                          \
  }

#define MP_EPI(mt, pi)                                                         \
  _Pragma("unroll")                                                            \
  for (int nt = 0; nt < 2; ++nt) {                                             \
    const int col = ng * 32 + nt * 16 + fr;                                    \
    const float* src = &xch[(((mt) * 8 + ng * 2 + nt) * 16) * 17];             \
    _Pragma("unroll")                                                          \
    for (int j = 0; j < 4; ++j) {                                              \
      const int m = (mt) * 16 + ks * 4 + j;                                    \
      if (m < L) {                                                             \
        float v = acc[mt][nt][j] + src[(ks * 4 + j) * 17 + fr];                \
        float nv = pf[pi][nt][j] + fmaxf(v, 0.f);                              \
        xb[(long)i * rowStride + (long)m * posStride + col] = nv;              \
        int br = m + 4;                                                        \
        int byte = (br * 256 + col * 2) ^ ((br & 7) << 4);                     \
        *(unsigned short*)(nxtb + byte) = f2bf(nv);                            \
      }                                                                        \
    }                                                                          \
  }

  for (int s = 1; s <= nsteps; ++s) {
    const char* curb = (const char*)rowbuf + (((s & 1) ^ 1) * MPBUF) * 2;
    char* nxtb = (char*)rowbuf + ((s & 1) * MPBUF) * 2;
    const int i = i0 + s * di;

    // prefetch x2[row i] for this wave's epilogue tiles (hidden under MFMAs)
    float pf[MTE][2][4];
    if (kh == 0) {
#pragma unroll
      for (int mt = 0; mt < MH; ++mt) { MP_PF(mt, mt) }
    } else {
#pragma unroll
      for (int mt = MH; mt < MT; ++mt) { MP_PF(mt, mt - MH) }
    }

    f32x4 acc[MT][2];
#pragma unroll
    for (int mt = 0; mt < MT; ++mt) {
      acc[mt][0] = (f32x4){0.f, 0.f, 0.f, 0.f};
      acc[mt][1] = (f32x4){0.f, 0.f, 0.f, 0.f};
    }

#pragma unroll
    for (int kk = 0; kk < 18; ++kk) {
      const int k0 = kh * 576 + kk * 32;
      const int tap = k0 >> 7;
      const int colb = ((k0 & 127) + ks * 8) * 2;
      const int br0 = fr + tap;
      const int byte0 = (br0 * 256 + colb) ^ ((br0 & 7) << 4);  // (br+16)&7 == br&7
#pragma unroll
      for (int mt = 0; mt < MT; ++mt) {
        bf16x8 af = *(const bf16x8*)(curb + byte0 + mt * 4096);
        acc[mt][0] = __builtin_amdgcn_mfma_f32_16x16x32_bf16(af, bfrag[0][kk], acc[mt][0], 0, 0, 0);
        acc[mt][1] = __builtin_amdgcn_mfma_f32_16x16x32_bf16(af, bfrag[1][kk], acc[mt][1], 0, 0, 0);
      }
    }

    // write partials for the m-tiles the OTHER k-half will epilogue
    if (kh == 0) {
#pragma unroll
      for (int mt = MH; mt < MT; ++mt) {
#pragma unroll
        for (int nt = 0; nt < 2; ++nt) {
          float* dst = &xch[((mt * 8 + ng * 2 + nt) * 16) * 17];
#pragma unroll
          for (int j = 0; j < 4; ++j)
            dst[(ks * 4 + j) * 17 + fr] = acc[mt][nt][j];
        }
      }
    } else {
#pragma unroll
      for (int mt = 0; mt < MH; ++mt) {
#pragma unroll
        for (int nt = 0; nt < 2; ++nt) {
          float* dst = &xch[((mt * 8 + ng * 2 + nt) * 16) * 17];
#pragma unroll
          for (int j = 0; j < 4; ++j)
            dst[(ks * 4 + j) * 17 + fr] = acc[mt][nt][j];
        }
      }
    }
    __syncthreads();
    // epilogue: own acc + xch -> relu -> store to x2 + next row into LDS
    if (kh == 0) {
#pragma unroll
      for (int mt = 0; mt < MH; ++mt) { MP_EPI(mt, mt) }
    } else {
#pragma unroll
      for (int mt = MH; mt < MT; ++mt) { MP_EPI(mt, mt - MH) }
    }
    __syncthreads();
  }
#undef MP_PF
#undef MP_EPI
}

// ---------------- segmentation head: 128 -> 5 + bias ----------------
__global__ __launch_bounds__(256) void seg_head(
    const float* __restrict__ xn, const float* __restrict__ w_seg,
    const float* __restrict__ b_seg, float* __restrict__ logits)
{
  __shared__ float ws[128 * 5];
  __shared__ float xs[32][129];
  const int tid = threadIdx.x;
  for (int i = tid; i < 640; i += 256) ws[i] = w_seg[i];
  const int pos0 = blockIdx.x * 32;
  for (int idx = tid; idx < 32 * 32; idx += 256) {
    int r = idx >> 5, q = idx & 31;
    float4 v = *(const float4*)(xn + (long)(pos0 + r) * 128 + q * 4);
    xs[r][q*4+0]=v.x; xs[r][q*4+1]=v.y; xs[r][q*4+2]=v.z; xs[r][q*4+3]=v.w;
  }
  __syncthreads();
  int r = tid >> 3, f = tid & 7;
  if (f < 5) {
    float acc = b_seg[f];
#pragma unroll 4
    for (int ci = 0; ci < 128; ++ci) acc = fmaf(xs[r][ci], ws[ci*5 + f], acc);
    logits[(long)(pos0 + r) * 5 + f] = acc;
  }
}

// ---------------- softmax + 2x2 mean pool ----------------
__global__ __launch_bounds__(256) void softpool(const float* __restrict__ logits, float* __restrict__ p)
{
  int idx = blockIdx.x * 256 + threadIdx.x;
  if (idx >= 16 * 18 * 50) return;
  int ww = idx % 50, hh = (idx / 50) % 18, b = idx / 900;
  float avg[5] = {0,0,0,0,0};
#pragma unroll
  for (int i = 0; i < 2; ++i)
#pragma unroll
    for (int j = 0; j < 2; ++j) {
      const float* L = logits + ((long)((b*36 + hh*2 + i) * 100) + ww*2 + j) * 5;
      float l0=L[0], l1=L[1], l2=L[2], l3=L[3], l4=L[4];
      float m = fmaxf(fmaxf(fmaxf(l0,l1), fmaxf(l2,l3)), l4);
      float e0=expf(l0-m), e1=expf(l1-m), e2=expf(l2-m), e3=expf(l3-m), e4=expf(l4-m);
      float inv = 1.f / (e0+e1+e2+e3+e4);
      avg[0] += e0*inv; avg[1] += e1*inv; avg[2] += e2*inv; avg[3] += e3*inv; avg[4] += e4*inv;
    }
  float* dst = p + (long)b * 4500 + (hh * 50 + ww) * 5;
#pragma unroll
  for (int f = 0; f < 5; ++f) dst[f] = avg[f] * 0.25f;
}

// ---------------- fc1 ----------------
__global__ __launch_bounds__(128) void fc1_kernel(
    const float* __restrict__ p, const float* __restrict__ w,
    const float* __restrict__ bias, float* __restrict__ z)
{
  __shared__ float ps[4500];
  const int b = blockIdx.x, tid = threadIdx.x;
  for (int i = tid; i < 4500; i += 128) ps[i] = p[(long)b * 4500 + i];
  __syncthreads();
  float acc = bias[tid];
#pragma unroll 4
  for (int m = 0; m < 4500; ++m) acc = fmaf(ps[m], w[(long)m * 128 + tid], acc);
  z[b * 128 + tid] = fmaxf(acc, 0.f);
}

// ---------------- fc2 ----------------
__global__ void fc2_kernel(const float* __restrict__ z, const float* __restrict__ w,
                           const float* __restrict__ bias, float* __restrict__ out)
{
  int t = threadIdx.x;
  if (t >= 64) return;
  int b = t >> 2, j = t & 3;
  float acc = bias[j];
#pragma unroll 4
  for (int n = 0; n < 128; ++n) acc = fmaf(z[b*128 + n], w[n*4 + j], acc);
  out[b*4 + j] = acc;
}

// ---------------- 8x bilinear resize ----------------
__global__ __launch_bounds__(256) void resize_bilinear(
    const float* __restrict__ logits, float* __restrict__ out)
{
  int idx = blockIdx.x * 256 + threadIdx.x;
  if (idx >= 18432000) return;
  int f = idx % 5;
  int t = idx / 5;
  int ow = t % 800; t /= 800;
  int oh = t % 288;
  int b = t / 288;
  float sh = (oh + 0.5f) * 0.125f - 0.5f;
  float sw = (ow + 0.5f) * 0.125f - 0.5f;
  int h0 = (int)floorf(sh); float fh = sh - (float)h0;
  int w0 = (int)floorf(sw); float fw = sw - (float)w0;
  int h1 = min(h0 + 1, 35); h0 = max(h0, 0);
  int w1 = min(w0 + 1, 99); w0 = max(w0, 0);
  const float* Lb = logits + (long)b * 36 * 100 * 5 + f;
  float v00 = Lb[(h0*100 + w0)*5], v01 = Lb[(h0*100 + w1)*5];
  float v10 = Lb[(h1*100 + w0)*5], v11 = Lb[(h1*100 + w1)*5];
  float v = (1.f-fh) * ((1.f-fw)*v00 + fw*v01) + fh * ((1.f-fw)*v10 + fw*v11);
  out[idx] = v;
}

// ============================================================
extern "C" void kernel_launch(void* const* d_in, const int* in_sizes, int n_in,
                              void* d_out, int out_size, void* d_ws, size_t ws_size,
                              hipStream_t stream)
{
  (void)in_sizes; (void)n_in; (void)out_size;
  const float* features = (const float*)d_in[0];
  const float* w_conv1  = (const float*)d_in[1];
  const float* bn1_s    = (const float*)d_in[2];
  const float* bn1_b    = (const float*)d_in[3];
  const float* w_conv2  = (const float*)d_in[4];
  const float* bn2_s    = (const float*)d_in[5];
  const float* bn2_b    = (const float*)d_in[6];
  const float* w_vf     = (const float*)d_in[7];
  const float* w_vr     = (const float*)d_in[8];
  const float* w_hf     = (const float*)d_in[9];
  const float* w_hr     = (const float*)d_in[10];
  const float* w_seg    = (const float*)d_in[11];
  const float* b_seg    = (const float*)d_in[12];
  const float* w_fc1    = (const float*)d_in[13];
  const float* b_fc1    = (const float*)d_in[14];
  const float* w_fc2    = (const float*)d_in[15];
  const float* b_fc2    = (const float*)d_in[16];

  char* ws = (char*)d_ws;
  unsigned short* x1  = (unsigned short*)ws;                // 117,964,800 B bf16
  unsigned short* w1t = (unsigned short*)(ws + 117964800);  // overlaps x2 (dead until conv2)
  float* x2     = (float*)(ws + 117964800);                 // 29,491,200 B f32
  float* logits = (float*)(ws + 147456000);                 // 1,152,000 B
  unsigned short* wtmp = (unsigned short*)(ws + 147456000); // 1,179,648 B (dead until MP done)
  float* pbuf   = (float*)(ws + 148608000);                 // 288,000 B
  float* zbuf   = (float*)(ws + 148896000);                 // 8,192 B
  float* stats  = (float*)(ws + 148904192);                 // 9,216 B
  float* ab1    = (float*)(ws + 148913408);                 // 8,192 B
  float* ab2    = (float*)(ws + 148921600);                 // 1,024 B
  unsigned short* w2t = (unsigned short*)(ws + 148922624);  // 262,144 B -> end 149,184,768
  unsigned short* in_pad = (unsigned short*)(ws + 149184768); // 77,856,768 B (optional)
  const bool use_pad = ws_size >= 227041536ULL;
  float* outf   = (float*)d_out;

  hipMemsetAsync(stats, 0, 2304 * sizeof(float), stream);
  convert_w1t<<<2304, 256, 0, stream>>>(w_conv1, w1t);
  convert_w2t<<<64, 256, 0, stream>>>(w_conv2, w2t);
  convert_wmp<<<72, 256, 0, stream>>>(w_vf, wtmp + 0 * 147456);
  convert_wmp<<<72, 256, 0, stream>>>(w_vr, wtmp + 1 * 147456);
  convert_wmp<<<72, 256, 0, stream>>>(w_hf, wtmp + 2 * 147456);
  convert_wmp<<<72, 256, 0, stream>>>(w_hr, wtmp + 3 * 147456);

  if (use_pad) {
    pad_features<<<19008, 256, 0, stream>>>(features, in_pad);
    conv1_mfma2<<<3600, 256, 0, stream>>>(in_pad, w1t, x1);
  } else {
    conv1_mfma<<<dim3(8, 450), 256, 0, stream>>>(features, w1t, x1);
  }
  stats1<<<512, 256, 0, stream>>>(x1, stats, stats + 1024);
  finalize_bn<<<4, 256, 0, stream>>>(stats, stats + 1024, bn1_s, bn1_b, ab1, 1024, 1.0f/57600.0f);
  bnrelu_x1<<<28800, 256, 0, stream>>>(x1, ab1);
  gemm_mfma_128<<<450, 256, 0, stream>>>(x1, w2t, x2, 1024);
  stats2<<<256, 256, 0, stream>>>(x2, stats + 2048, stats + 2176);
  finalize_bn<<<1, 128, 0, stream>>>(stats + 2048, stats + 2176, bn2_s, bn2_b, ab2, 128, 1.0f/57600.0f);
  apply_bn<<<7200, 256, 0, stream>>>(x2, ab2);

  // fused message passing: 4 launches, weights in VGPRs, prefetched epilogue
  mp_fused2<7,3><<<NB, 512, 0, stream>>>(x2, wtmp + 0 * 147456, 100, 128,   12800, 0,  +1, 35);
  mp_fused2<7,3><<<NB, 512, 0, stream>>>(x2, wtmp + 1 * 147456, 100, 128,   12800, 35, -1, 35);
  mp_fused2<3,1><<<NB, 512, 0, stream>>>(x2, wtmp + 2 * 147456, 36,  12800, 128,   0,  +1, 99);
  mp_fused2<3,1><<<NB, 512, 0, stream>>>(x2, wtmp + 3 * 147456, 36,  12800, 128,   99, -1, 99);

  seg_head<<<1800, 256, 0, stream>>>(x2, w_seg, b_seg, logits);
  softpool<<<57, 256, 0, stream>>>(logits, pbuf);
  fc1_kernel<<<16, 128, 0, stream>>>(pbuf, w_fc1, b_fc1, zbuf);
  fc2_kernel<<<1, 64, 0, stream>>>(zbuf, w_fc2, b_fc2, outf + 18432000);
  resize_bilinear<<<72000, 256, 0, stream>>>(logits, outf);
}

// Round 6
// 3555.439 us; speedup vs baseline: 6.1333x; 1.0741x over previous
//
#include <hip/hip_runtime.h>
#include <hip/hip_bf16.h>

#define NB 16
#define NPOS 57600

typedef short bf16x8 __attribute__((ext_vector_type(8)));
typedef float f32x4 __attribute__((ext_vector_type(4)));

__device__ __forceinline__ float bf2f(unsigned short u) {
  union { unsigned int i; float f; } c; c.i = ((unsigned int)u) << 16; return c.f;
}
// round-to-nearest-even f32 -> bf16 bits
__device__ __forceinline__ unsigned short f2bf(float f) {
  union { float f; unsigned int i; } c; c.f = f;
  unsigned int x = c.i;
  x += 0x7fffu + ((x >> 16) & 1u);
  return (unsigned short)(x >> 16);
}
__device__ __forceinline__ unsigned int pk2(float lo, float hi) {
  return (unsigned int)f2bf(lo) | ((unsigned int)f2bf(hi) << 16);
}

__device__ __forceinline__ void gload_lds16(const void* g, void* l) {
  __builtin_amdgcn_global_load_lds(
      (const __attribute__((address_space(1))) unsigned int*)(g),
      (__attribute__((address_space(3))) unsigned int*)(l), 16, 0, 0);
}

// ---------------- weight conversions (one-time, tiny) ----------------
// w1 (4608,1024) f32 -> w1t (1024,4608) bf16
__global__ __launch_bounds__(256) void convert_w1t(const float* __restrict__ w,
                                                   unsigned short* __restrict__ wt)
{
  int idx = blockIdx.x * 256 + threadIdx.x;     // 589824 jobs
  int n = idx & 1023;
  int k0 = (idx >> 10) * 8;
  unsigned int o[4];
#pragma unroll
  for (int j = 0; j < 4; ++j) {
    float lo = w[(long)(k0 + 2*j)     * 1024 + n];
    float hi = w[(long)(k0 + 2*j + 1) * 1024 + n];
    o[j] = pk2(lo, hi);
  }
  *(uint4*)(wt + (long)n * 4608 + k0) = make_uint4(o[0], o[1], o[2], o[3]);
}

// w2 (1024,128) f32 -> w2t (128,1024) bf16
__global__ __launch_bounds__(256) void convert_w2t(const float* __restrict__ w,
                                                   unsigned short* __restrict__ wt)
{
  int idx = blockIdx.x * 256 + threadIdx.x;     // 16384 jobs
  int n = idx & 127;
  int k0 = (idx >> 7) * 8;
  unsigned int o[4];
#pragma unroll
  for (int j = 0; j < 4; ++j) {
    float lo = w[(long)(k0 + 2*j)     * 128 + n];
    float hi = w[(long)(k0 + 2*j + 1) * 128 + n];
    o[j] = pk2(lo, hi);
  }
  *(uint4*)(wt + (long)n * 1024 + k0) = make_uint4(o[0], o[1], o[2], o[3]);
}

// w_mp (9,128,128)[tap][ci][co] f32 -> wt (128,1152)[co][tap*128+ci] bf16
__global__ __launch_bounds__(256) void convert_wmp(const float* __restrict__ w,
                                                   unsigned short* __restrict__ wt)
{
  int idx = blockIdx.x * 256 + threadIdx.x;     // 18432 jobs
  if (idx >= 18432) return;
  int co = idx & 127;
  int kg = idx >> 7;                            // 0..143
  int k0 = kg * 8;
  int tap = k0 >> 7, ci0 = k0 & 127;
  const float* src = w + (long)tap * 16384 + (long)ci0 * 128 + co;
  unsigned int o[4];
#pragma unroll
  for (int j = 0; j < 4; ++j)
    o[j] = pk2(src[(2*j) * 128], src[(2*j+1) * 128]);
  *(uint4*)(wt + (long)co * 1152 + k0) = make_uint4(o[0], o[1], o[2], o[3]);
}

// ---------------- pad+convert features: f32 (16,36,100,512) -> bf16 (16,44,108,512) ----------------
__global__ __launch_bounds__(256) void pad_features(const float* __restrict__ src,
                                                    unsigned short* __restrict__ dst)
{
  long idx = (long)blockIdx.x * 256 + threadIdx.x;   // 4,866,048 jobs (8 ch each)
  if (idx >= 16L * 44 * 108 * 64) return;
  int c8 = (int)(idx & 63);
  long pos = idx >> 6;
  int wp = (int)(pos % 108); pos /= 108;
  int hp = (int)(pos % 44);
  int b  = (int)(pos / 44);
  uint4 o = make_uint4(0u, 0u, 0u, 0u);
  if (hp >= 4 && hp < 40 && wp >= 4 && wp < 104) {
    const float* s = src + (((long)b * 36 + (hp - 4)) * 100 + (wp - 4)) * 512 + c8 * 8;
    float4 v0 = *(const float4*)s;
    float4 v1 = *(const float4*)(s + 4);
    o = make_uint4(pk2(v0.x, v0.y), pk2(v0.z, v0.w), pk2(v1.x, v1.y), pk2(v1.z, v1.w));
  }
  *(uint4*)(dst + (((long)b * 44 + hp) * 108 + wp) * 512 + c8 * 8) = o;
}

// ============================================================
// conv1 v2: padded bf16 input, pure global_load_lds staging,
// XCD-chunked swizzle. GEMM M=57600, K=4608, N=1024.
// ============================================================
__global__ __launch_bounds__(256) void conv1_mfma2(
    const unsigned short* __restrict__ inp,  // (16,44,108,512) bf16 padded
    const unsigned short* __restrict__ w1t,  // (1024,4608) bf16 [n][k]
    unsigned short* __restrict__ x1)         // (57600,1024) bf16
{
  __shared__ unsigned short Al[128 * 32];
  __shared__ unsigned short Bl[128 * 32];
  const int tid  = threadIdx.x;
  const int lane = tid & 63;
  const int wave = tid >> 6;
  const int wm = wave >> 1, wn = wave & 1;
  // bijective XCD-chunked swizzle: 3600 blocks = 8 chunks x 450
  const int bid  = blockIdx.x;
  const int nbid = (bid & 7) * 450 + (bid >> 3);
  const int n0 = (nbid & 7) * 128;      // n fastest: 8 n-blocks share A-panel on same XCD
  const int m0 = (nbid >> 3) * 128;

  long aoff[2];
  const unsigned short* bsrc[2];
#pragma unroll
  for (int q = 0; q < 2; ++q) {
    int e = q * 256 + tid;
    int row = e >> 2;
    int kl  = (e & 3) * 8;
    int m = m0 + row;
    int w = m % 100, h = (m / 100) % 36, b = m / 3600;
    aoff[q] = (((long)b * 44 + h + 4) * 108 + (w + 4)) * 512 + kl;
    bsrc[q] = w1t + (long)(n0 + row) * 4608 + kl;
  }

  f32x4 acc[4][4];
#pragma unroll
  for (int i = 0; i < 4; ++i)
#pragma unroll
    for (int j = 0; j < 4; ++j) acc[i][j] = (f32x4){0.f, 0.f, 0.f, 0.f};

  const int fr = lane & 15;
  const int fk = (lane >> 4) * 8;
  const unsigned short* Alrd = Al + (wm * 64 + fr) * 32 + fk;
  const unsigned short* Blrd = Bl + (wn * 64 + fr) * 32 + fk;

  for (int k0 = 0; k0 < 4608; k0 += 32) {
    const int tap = k0 >> 9;
    const int ci0 = k0 & 511;
    const int dh = (tap / 3) * 4 - 4, dw = (tap % 3) * 4 - 4;
    const long delta = (long)(dh * 108 + dw) * 512 + ci0;
    __syncthreads();
#pragma unroll
    for (int q = 0; q < 2; ++q) {
      gload_lds16(inp + aoff[q] + delta, Al + (q * 256 + tid) * 8);
      gload_lds16(bsrc[q] + k0,          Bl + (q * 256 + tid) * 8);
    }
    __syncthreads();
    bf16x8 af[4], bfr[4];
#pragma unroll
    for (int m = 0; m < 4; ++m) af[m]  = *(const bf16x8*)(Alrd + m * 16 * 32);
#pragma unroll
    for (int n = 0; n < 4; ++n) bfr[n] = *(const bf16x8*)(Blrd + n * 16 * 32);
#pragma unroll
    for (int m = 0; m < 4; ++m)
#pragma unroll
      for (int n = 0; n < 4; ++n)
        acc[m][n] = __builtin_amdgcn_mfma_f32_16x16x32_bf16(af[m], bfr[n], acc[m][n], 0, 0, 0);
  }
  const int r0 = (lane >> 4) * 4;
#pragma unroll
  for (int m = 0; m < 4; ++m) {
    int row = m0 + wm * 64 + m * 16 + r0;
#pragma unroll
    for (int n = 0; n < 4; ++n) {
      int col = n0 + wn * 64 + n * 16 + fr;
#pragma unroll
      for (int j = 0; j < 4; ++j)
        x1[(long)(row + j) * 1024 + col] = f2bf(acc[m][n][j]);
    }
  }
}

// ============================================================
// conv1 v1 (fallback when ws too small for padded features)
// ============================================================
__global__ __launch_bounds__(256) void conv1_mfma(
    const float* __restrict__ in,
    const unsigned short* __restrict__ w1t,
    unsigned short* __restrict__ x1)
{
  __shared__ unsigned short Al[128 * 32];
  __shared__ unsigned short Bl[128 * 32];
  const int tid  = threadIdx.x;
  const int lane = tid & 63;
  const int wave = tid >> 6;
  const int wm = wave >> 1, wn = wave & 1;
  const int m0 = blockIdx.y * 128;
  const int n0 = blockIdx.x * 128;

  int akl[2], ab_[2], ah_[2], aw_[2];
  const unsigned short* bsrc[2];
#pragma unroll
  for (int q = 0; q < 2; ++q) {
    int e = q * 256 + tid;
    int row = e >> 2;
    akl[q]  = (e & 3) * 8;
    int m = m0 + row;
    aw_[q] = m % 100;
    ah_[q] = (m / 100) % 36;
    ab_[q] = m / 3600;
    bsrc[q] = w1t + (long)(n0 + row) * 4608 + akl[q];
  }

  f32x4 acc[4][4];
#pragma unroll
  for (int i = 0; i < 4; ++i)
#pragma unroll
    for (int j = 0; j < 4; ++j) acc[i][j] = (f32x4){0.f, 0.f, 0.f, 0.f};

  const int fr = lane & 15;
  const int fk = (lane >> 4) * 8;
  const unsigned short* Alrd = Al + (wm * 64 + fr) * 32 + fk;
  const unsigned short* Blrd = Bl + (wn * 64 + fr) * 32 + fk;

  for (int k0 = 0; k0 < 4608; k0 += 32) {
    const int tap = k0 >> 9;
    const int ci0 = k0 & 511;
    const int dh = (tap / 3) * 4 - 4, dw = (tap % 3) * 4 - 4;
    unsigned int apk[2][4];
#pragma unroll
    for (int q = 0; q < 2; ++q) {
      int ih = ah_[q] + dh, iw = aw_[q] + dw;
      if ((unsigned)ih < 36u && (unsigned)iw < 100u) {
        const float* s = in + ((((long)ab_[q] * 36 + ih) * 100 + iw) << 9) + ci0 + akl[q];
        float4 v0 = *(const float4*)s;
        float4 v1 = *(const float4*)(s + 4);
        apk[q][0] = pk2(v0.x, v0.y); apk[q][1] = pk2(v0.z, v0.w);
        apk[q][2] = pk2(v1.x, v1.y); apk[q][3] = pk2(v1.z, v1.w);
      } else {
        apk[q][0] = apk[q][1] = apk[q][2] = apk[q][3] = 0u;
      }
    }
    __syncthreads();
#pragma unroll
    for (int q = 0; q < 2; ++q) {
      *(uint4*)(Al + (q * 256 + tid) * 8) = *(uint4*)apk[q];
      gload_lds16(bsrc[q] + k0, Bl + (q * 256 + tid) * 8);
    }
    __syncthreads();
    bf16x8 af[4], bfr[4];
#pragma unroll
    for (int m = 0; m < 4; ++m) af[m]  = *(const bf16x8*)(Alrd + m * 16 * 32);
#pragma unroll
    for (int n = 0; n < 4; ++n) bfr[n] = *(const bf16x8*)(Blrd + n * 16 * 32);
#pragma unroll
    for (int m = 0; m < 4; ++m)
#pragma unroll
      for (int n = 0; n < 4; ++n)
        acc[m][n] = __builtin_amdgcn_mfma_f32_16x16x32_bf16(af[m], bfr[n], acc[m][n], 0, 0, 0);
  }
  const int r0 = (lane >> 4) * 4;
#pragma unroll
  for (int m = 0; m < 4; ++m) {
    int row = m0 + wm * 64 + m * 16 + r0;
#pragma unroll
    for (int n = 0; n < 4; ++n) {
      int col = n0 + wn * 64 + n * 16 + fr;
#pragma unroll
      for (int j = 0; j < 4; ++j)
        x1[(long)(row + j) * 1024 + col] = f2bf(acc[m][n][j]);
    }
  }
}

// ============================================================
// conv2: bf16 GEMM A(M,1024) x Bt(128,1024) -> C(M,128) f32
// ============================================================
__global__ __launch_bounds__(256) void gemm_mfma_128(
    const unsigned short* __restrict__ A,
    const unsigned short* __restrict__ Bt,
    float* __restrict__ C, int K)
{
  __shared__ unsigned short Al[128 * 32];
  __shared__ unsigned short Bl[128 * 32];
  const int tid  = threadIdx.x;
  const int lane = tid & 63;
  const int wave = tid >> 6;
  const int wm = wave >> 1, wn = wave & 1;
  const int m0 = blockIdx.x * 128;

  const unsigned short* asrc[2];
  const unsigned short* bsrc[2];
#pragma unroll
  for (int q = 0; q < 2; ++q) {
    int e = q * 256 + tid;
    int row = e >> 2;
    int kl  = (e & 3) * 8;
    asrc[q] = A  + (long)(m0 + row) * K + kl;
    bsrc[q] = Bt + (long)row * K + kl;
  }

  f32x4 acc[4][4];
#pragma unroll
  for (int i = 0; i < 4; ++i)
#pragma unroll
    for (int j = 0; j < 4; ++j) acc[i][j] = (f32x4){0.f, 0.f, 0.f, 0.f};

  const int fr = lane & 15;
  const int fk = (lane >> 4) * 8;
  const unsigned short* Alrd = Al + (wm * 64 + fr) * 32 + fk;
  const unsigned short* Blrd = Bl + (wn * 64 + fr) * 32 + fk;

  for (int k0 = 0; k0 < K; k0 += 32) {
    __syncthreads();
#pragma unroll
    for (int q = 0; q < 2; ++q) {
      gload_lds16(asrc[q] + k0, Al + (q * 256 + tid) * 8);
      gload_lds16(bsrc[q] + k0, Bl + (q * 256 + tid) * 8);
    }
    __syncthreads();
    bf16x8 af[4], bfr[4];
#pragma unroll
    for (int m = 0; m < 4; ++m) af[m]  = *(const bf16x8*)(Alrd + m * 16 * 32);
#pragma unroll
    for (int n = 0; n < 4; ++n) bfr[n] = *(const bf16x8*)(Blrd + n * 16 * 32);
#pragma unroll
    for (int m = 0; m < 4; ++m)
#pragma unroll
      for (int n = 0; n < 4; ++n)
        acc[m][n] = __builtin_amdgcn_mfma_f32_16x16x32_bf16(af[m], bfr[n], acc[m][n], 0, 0, 0);
  }
  const int r0 = (lane >> 4) * 4;
#pragma unroll
  for (int m = 0; m < 4; ++m) {
    int row = m0 + wm * 64 + m * 16 + r0;
#pragma unroll
    for (int n = 0; n < 4; ++n) {
      int col = wn * 64 + n * 16 + fr;
#pragma unroll
      for (int j = 0; j < 4; ++j)
        C[(long)(row + j) * 128 + col] = acc[m][n][j];
    }
  }
}

// ---------------- per-channel stats over x1 (bf16) ----------------
__global__ __launch_bounds__(256) void stats1(const unsigned short* __restrict__ x1,
                                              float* __restrict__ sum, float* __restrict__ ssq)
{
  const int tid = threadIdx.x;
  const int c0 = tid * 4;
  float s0=0,s1=0,s2=0,s3=0,q0=0,q1=0,q2=0,q3=0;
  for (int r = blockIdx.x; r < NPOS; r += gridDim.x) {
    uint2 v = *(const uint2*)(x1 + (long)r * 1024 + c0);
    float f0 = bf2f(v.x & 0xffffu), f1 = bf2f(v.x >> 16);
    float f2 = bf2f(v.y & 0xffffu), f3 = bf2f(v.y >> 16);
    s0 += f0; q0 += f0*f0;  s1 += f1; q1 += f1*f1;
    s2 += f2; q2 += f2*f2;  s3 += f3; q3 += f3*f3;
  }
  atomicAdd(&sum[c0+0], s0); atomicAdd(&ssq[c0+0], q0);
  atomicAdd(&sum[c0+1], s1); atomicAdd(&ssq[c0+1], q1);
  atomicAdd(&sum[c0+2], s2); atomicAdd(&ssq[c0+2], q2);
  atomicAdd(&sum[c0+3], s3); atomicAdd(&ssq[c0+3], q3);
}

__global__ void finalize_bn(const float* __restrict__ sum, const float* __restrict__ ssq,
                            const float* __restrict__ scale, const float* __restrict__ bias,
                            float* __restrict__ ab, int C, float invN)
{
  int c = blockIdx.x * blockDim.x + threadIdx.x;
  if (c >= C) return;
  float mean = sum[c] * invN;
  float var  = ssq[c] * invN - mean * mean;
  float a = scale[c] * rsqrtf(var + 1e-5f);
  ab[c] = a;
  ab[C + c] = bias[c] - mean * a;
}

// ---------------- relu(bn1(x1)) in place on bf16 x1 ----------------
__global__ __launch_bounds__(256) void bnrelu_x1(unsigned short* __restrict__ x1,
                                                 const float* __restrict__ ab)
{
  long base = ((long)blockIdx.x * 256 + threadIdx.x) * 8;
  int c0 = (int)(base & 1023);
  uint4 v = *(uint4*)(x1 + base);
  unsigned int w[4] = {v.x, v.y, v.z, v.w};
  unsigned int o[4];
#pragma unroll
  for (int j = 0; j < 4; ++j) {
    int c = c0 + j * 2;
    float lo = bf2f((unsigned short)(w[j] & 0xffffu));
    float hi = bf2f((unsigned short)(w[j] >> 16));
    lo = fmaxf(fmaf(lo, ab[c],     ab[1024 + c]),     0.f);
    hi = fmaxf(fmaf(hi, ab[c + 1], ab[1024 + c + 1]), 0.f);
    o[j] = pk2(lo, hi);
  }
  *(uint4*)(x1 + base) = make_uint4(o[0], o[1], o[2], o[3]);
}

// ---------------- stats over x2 (fp32, 128 ch) ----------------
__global__ __launch_bounds__(256) void stats2(const float* __restrict__ x2,
                                              float* __restrict__ sum, float* __restrict__ ssq)
{
  const int c = threadIdx.x & 127;
  const int g = threadIdx.x >> 7;
  float s = 0.f, q = 0.f;
  for (int r = blockIdx.x * 2 + g; r < NPOS; r += gridDim.x * 2) {
    float v = x2[(long)r * 128 + c];
    s += v; q += v * v;
  }
  atomicAdd(&sum[c], s); atomicAdd(&ssq[c], q);
}

// ---------------- apply bn2 + relu in place ----------------
__global__ __launch_bounds__(256) void apply_bn(float* __restrict__ x, const float* __restrict__ ab)
{
  int idx = (blockIdx.x * 256 + threadIdx.x) * 4;
  if (idx >= NPOS * 128) return;
  int c = idx & 127;
  float4 v = *(float4*)(x + idx);
  v.x = fmaxf(fmaf(v.x, ab[c+0], ab[128+c+0]), 0.f);
  v.y = fmaxf(fmaf(v.y, ab[c+1], ab[128+c+1]), 0.f);
  v.z = fmaxf(fmaf(v.z, ab[c+2], ab[128+c+2]), 0.f);
  v.w = fmaxf(fmaf(v.w, ab[c+3], ab[128+c+3]), 0.f);
  *(float4*)(x + idx) = v;
}

// ============================================================
// Fused message passing: weights resident in VGPRs.
// __launch_bounds__(512, 2): 2 waves/EU min -> 256-VGPR cap, so
// bfrag(144) + acc(<=56) + temps fits WITHOUT spilling (R5 ran at
// VGPR=128 and spilled everything to scratch -> 736us/dispatch).
// 8 waves = 4 n-groups x 2 k-halves; per step: MFMA partials ->
// LDS exchange -> direct-RMW epilogue + bf16 row into next buffer.
// ============================================================
#define MPROWS 120
#define MPBUF (MPROWS * 128)   // halfwords per row buffer
template<int MT, int MH>
__global__ __launch_bounds__(512, 2) void mp_fused2(
    float* __restrict__ x2, const unsigned short* __restrict__ wt,
    const int L, const int posStride, const int rowStride,
    const int i0, const int di, const int nsteps)
{
  __shared__ unsigned short rowbuf[2 * MPBUF];       // 61440 B
  __shared__ float xch[MT * 8 * 16 * 17];            // partial-sum exchange (+1 pad)
  const int tid  = threadIdx.x;
  const int lane = tid & 63;
  const int wave = tid >> 6;        // 0..7
  const int ng   = wave & 3;        // n-group: cols ng*32 .. +31 (2 n-tiles)
  const int kh   = wave >> 2;       // k-half: k in [kh*576, kh*576+576)
  const int fr   = lane & 15;
  const int ks   = lane >> 4;       // 0..3
  float* xb = x2 + (long)blockIdx.x * 460800;

  // zero row buffers (halo rows stay zero forever)
  for (int i = tid; i < (2 * MPBUF) / 8; i += 512)
    *(uint4*)(rowbuf + i * 8) = make_uint4(0u, 0u, 0u, 0u);

  // B prologue: 36 x 16B per lane -> 144 VGPR, resident across all steps
  const unsigned short* wb = wt + (long)(ng * 32 + fr) * 1152 + kh * 576 + ks * 8;
  bf16x8 bfrag[2][18];
#pragma unroll
  for (int nt = 0; nt < 2; ++nt)
#pragma unroll
    for (int kk = 0; kk < 18; ++kk)
      bfrag[nt][kk] = *(const bf16x8*)(wb + nt * 16 * 1152 + kk * 32);

  __syncthreads();
  // load row i0 -> buf0 (bf16, swizzled); row i0 is never modified
  for (int e = tid * 4; e < L * 128; e += 2048) {
    int w = e >> 7, c = e & 127;
    float4 v = *(const float4*)(xb + (long)i0 * rowStride + (long)w * posStride + c);
    int br = w + 4;
    int byte = (br * 256 + c * 2) ^ ((br & 7) << 4);
    *(uint2*)((char*)rowbuf + byte) = make_uint2(pk2(v.x, v.y), pk2(v.z, v.w));
  }
  __syncthreads();

#define MP_EPI(mt)                                                             \
  _Pragma("unroll")                                                            \
  for (int nt = 0; nt < 2; ++nt) {                                             \
    const int col = ng * 32 + nt * 16 + fr;                                    \
    const float* src = &xch[(((mt) * 8 + ng * 2 + nt) * 16) * 17];             \
    _Pragma("unroll")                                                          \
    for (int j = 0; j < 4; ++j) {                                              \
      const int m = (mt) * 16 + ks * 4 + j;                                    \
      if (m < L) {                                                             \
        float v = acc[mt][nt][j] + src[(ks * 4 + j) * 17 + fr];                \
        long off = (long)i * rowStride + (long)m * posStride + col;            \
        float nv = xb[off] + fmaxf(v, 0.f);                                    \
        xb[off] = nv;                                                          \
        int br = m + 4;                                                        \
        int byte = (br * 256 + col * 2) ^ ((br & 7) << 4);                     \
        *(unsigned short*)(nxtb + byte) = f2bf(nv);                            \
      }                                                                        \
    }                                                                          \
  }

  for (int s = 1; s <= nsteps; ++s) {
    const char* curb = (const char*)rowbuf + (((s & 1) ^ 1) * MPBUF) * 2;
    char* nxtb = (char*)rowbuf + ((s & 1) * MPBUF) * 2;
    const int i = i0 + s * di;

    f32x4 acc[MT][2];
#pragma unroll
    for (int mt = 0; mt < MT; ++mt) {
      acc[mt][0] = (f32x4){0.f, 0.f, 0.f, 0.f};
      acc[mt][1] = (f32x4){0.f, 0.f, 0.f, 0.f};
    }

#pragma unroll
    for (int kk = 0; kk < 18; ++kk) {
      const int k0 = kh * 576 + kk * 32;
      const int tap = k0 >> 7;
      const int colb = ((k0 & 127) + ks * 8) * 2;
      const int br0 = fr + tap;
      const int byte0 = (br0 * 256 + colb) ^ ((br0 & 7) << 4);  // (br+16)&7 == br&7
#pragma unroll
      for (int mt = 0; mt < MT; ++mt) {
        bf16x8 af = *(const bf16x8*)(curb + byte0 + mt * 4096);
        acc[mt][0] = __builtin_amdgcn_mfma_f32_16x16x32_bf16(af, bfrag[0][kk], acc[mt][0], 0, 0, 0);
        acc[mt][1] = __builtin_amdgcn_mfma_f32_16x16x32_bf16(af, bfrag[1][kk], acc[mt][1], 0, 0, 0);
      }
    }

    // write partials for the m-tiles the OTHER k-half will epilogue
    if (kh == 0) {
#pragma unroll
      for (int mt = MH; mt < MT; ++mt) {
#pragma unroll
        for (int nt = 0; nt < 2; ++nt) {
          float* dst = &xch[((mt * 8 + ng * 2 + nt) * 16) * 17];
#pragma unroll
          for (int j = 0; j < 4; ++j)
            dst[(ks * 4 + j) * 17 + fr] = acc[mt][nt][j];
        }
      }
    } else {
#pragma unroll
      for (int mt = 0; mt < MH; ++mt) {
#pragma unroll
        for (int nt = 0; nt < 2; ++nt) {
          float* dst = &xch[((mt * 8 + ng * 2 + nt) * 16) * 17];
#pragma unroll
          for (int j = 0; j < 4; ++j)
            dst[(ks * 4 + j) * 17 + fr] = acc[mt][nt][j];
        }
      }
    }
    __syncthreads();
    // epilogue: own acc + xch -> relu -> RMW x2 + next row into LDS
    if (kh == 0) {
#pragma unroll
      for (int mt = 0; mt < MH; ++mt) { MP_EPI(mt) }
    } else {
#pragma unroll
      for (int mt = MH; mt < MT; ++mt) { MP_EPI(mt) }
    }
    __syncthreads();
  }
#undef MP_EPI
}

// ---------------- segmentation head: 128 -> 5 + bias ----------------
__global__ __launch_bounds__(256) void seg_head(
    const float* __restrict__ xn, const float* __restrict__ w_seg,
    const float* __restrict__ b_seg, float* __restrict__ logits)
{
  __shared__ float ws[128 * 5];
  __shared__ float xs[32][129];
  const int tid = threadIdx.x;
  for (int i = tid; i < 640; i += 256) ws[i] = w_seg[i];
  const int pos0 = blockIdx.x * 32;
  for (int idx = tid; idx < 32 * 32; idx += 256) {
    int r = idx >> 5, q = idx & 31;
    float4 v = *(const float4*)(xn + (long)(pos0 + r) * 128 + q * 4);
    xs[r][q*4+0]=v.x; xs[r][q*4+1]=v.y; xs[r][q*4+2]=v.z; xs[r][q*4+3]=v.w;
  }
  __syncthreads();
  int r = tid >> 3, f = tid & 7;
  if (f < 5) {
    float acc = b_seg[f];
#pragma unroll 4
    for (int ci = 0; ci < 128; ++ci) acc = fmaf(xs[r][ci], ws[ci*5 + f], acc);
    logits[(long)(pos0 + r) * 5 + f] = acc;
  }
}

// ---------------- softmax + 2x2 mean pool ----------------
__global__ __launch_bounds__(256) void softpool(const float* __restrict__ logits, float* __restrict__ p)
{
  int idx = blockIdx.x * 256 + threadIdx.x;
  if (idx >= 16 * 18 * 50) return;
  int ww = idx % 50, hh = (idx / 50) % 18, b = idx / 900;
  float avg[5] = {0,0,0,0,0};
#pragma unroll
  for (int i = 0; i < 2; ++i)
#pragma unroll
    for (int j = 0; j < 2; ++j) {
      const float* L = logits + ((long)((b*36 + hh*2 + i) * 100) + ww*2 + j) * 5;
      float l0=L[0], l1=L[1], l2=L[2], l3=L[3], l4=L[4];
      float m = fmaxf(fmaxf(fmaxf(l0,l1), fmaxf(l2,l3)), l4);
      float e0=expf(l0-m), e1=expf(l1-m), e2=expf(l2-m), e3=expf(l3-m), e4=expf(l4-m);
      float inv = 1.f / (e0+e1+e2+e3+e4);
      avg[0] += e0*inv; avg[1] += e1*inv; avg[2] += e2*inv; avg[3] += e3*inv; avg[4] += e4*inv;
    }
  float* dst = p + (long)b * 4500 + (hh * 50 + ww) * 5;
#pragma unroll
  for (int f = 0; f < 5; ++f) dst[f] = avg[f] * 0.25f;
}

// ---------------- fc1 ----------------
__global__ __launch_bounds__(128) void fc1_kernel(
    const float* __restrict__ p, const float* __restrict__ w,
    const float* __restrict__ bias, float* __restrict__ z)
{
  __shared__ float ps[4500];
  const int b = blockIdx.x, tid = threadIdx.x;
  for (int i = tid; i < 4500; i += 128) ps[i] = p[(long)b * 4500 + i];
  __syncthreads();
  float acc = bias[tid];
#pragma unroll 4
  for (int m = 0; m < 4500; ++m) acc = fmaf(ps[m], w[(long)m * 128 + tid], acc);
  z[b * 128 + tid] = fmaxf(acc, 0.f);
}

// ---------------- fc2 ----------------
__global__ void fc2_kernel(const float* __restrict__ z, const float* __restrict__ w,
                           const float* __restrict__ bias, float* __restrict__ out)
{
  int t = threadIdx.x;
  if (t >= 64) return;
  int b = t >> 2, j = t & 3;
  float acc = bias[j];
#pragma unroll 4
  for (int n = 0; n < 128; ++n) acc = fmaf(z[b*128 + n], w[n*4 + j], acc);
  out[b*4 + j] = acc;
}

// ---------------- 8x bilinear resize ----------------
__global__ __launch_bounds__(256) void resize_bilinear(
    const float* __restrict__ logits, float* __restrict__ out)
{
  int idx = blockIdx.x * 256 + threadIdx.x;
  if (idx >= 18432000) return;
  int f = idx % 5;
  int t = idx / 5;
  int ow = t % 800; t /= 800;
  int oh = t % 288;
  int b = t / 288;
  float sh = (oh + 0.5f) * 0.125f - 0.5f;
  float sw = (ow + 0.5f) * 0.125f - 0.5f;
  int h0 = (int)floorf(sh); float fh = sh - (float)h0;
  int w0 = (int)floorf(sw); float fw = sw - (float)w0;
  int h1 = min(h0 + 1, 35); h0 = max(h0, 0);
  int w1 = min(w0 + 1, 99); w0 = max(w0, 0);
  const float* Lb = logits + (long)b * 36 * 100 * 5 + f;
  float v00 = Lb[(h0*100 + w0)*5], v01 = Lb[(h0*100 + w1)*5];
  float v10 = Lb[(h1*100 + w0)*5], v11 = Lb[(h1*100 + w1)*5];
  float v = (1.f-fh) * ((1.f-fw)*v00 + fw*v01) + fh * ((1.f-fw)*v10 + fw*v11);
  out[idx] = v;
}

// ============================================================
extern "C" void kernel_launch(void* const* d_in, const int* in_sizes, int n_in,
                              void* d_out, int out_size, void* d_ws, size_t ws_size,
                              hipStream_t stream)
{
  (void)in_sizes; (void)n_in; (void)out_size;
  const float* features = (const float*)d_in[0];
  const float* w_conv1  = (const float*)d_in[1];
  const float* bn1_s    = (const float*)d_in[2];
  const float* bn1_b    = (const float*)d_in[3];
  const float* w_conv2  = (const float*)d_in[4];
  const float* bn2_s    = (const float*)d_in[5];
  const float* bn2_b    = (const float*)d_in[6];
  const float* w_vf     = (const float*)d_in[7];
  const float* w_vr     = (const float*)d_in[8];
  const float* w_hf     = (const float*)d_in[9];
  const float* w_hr     = (const float*)d_in[10];
  const float* w_seg    = (const float*)d_in[11];
  const float* b_seg    = (const float*)d_in[12];
  const float* w_fc1    = (const float*)d_in[13];
  const float* b_fc1    = (const float*)d_in[14];
  const float* w_fc2    = (const float*)d_in[15];
  const float* b_fc2    = (const float*)d_in[16];

  char* ws = (char*)d_ws;
  unsigned short* x1  = (unsigned short*)ws;                // 117,964,800 B bf16
  unsigned short* w1t = (unsigned short*)(ws + 117964800);  // overlaps x2 (dead until conv2)
  float* x2     = (float*)(ws + 117964800);                 // 29,491,200 B f32
  float* logits = (float*)(ws + 147456000);                 // 1,152,000 B
  unsigned short* wtmp = (unsigned short*)(ws + 147456000); // 1,179,648 B (dead until MP done)
  float* pbuf   = (float*)(ws + 148608000);                 // 288,000 B
  float* zbuf   = (float*)(ws + 148896000);                 // 8,192 B
  float* stats  = (float*)(ws + 148904192);                 // 9,216 B
  float* ab1    = (float*)(ws + 148913408);                 // 8,192 B
  float* ab2    = (float*)(ws + 148921600);                 // 1,024 B
  unsigned short* w2t = (unsigned short*)(ws + 148922624);  // 262,144 B -> end 149,184,768
  unsigned short* in_pad = (unsigned short*)(ws + 149184768); // 77,856,768 B (optional)
  const bool use_pad = ws_size >= 227041536ULL;
  float* outf   = (float*)d_out;

  hipMemsetAsync(stats, 0, 2304 * sizeof(float), stream);
  convert_w1t<<<2304, 256, 0, stream>>>(w_conv1, w1t);
  convert_w2t<<<64, 256, 0, stream>>>(w_conv2, w2t);
  convert_wmp<<<72, 256, 0, stream>>>(w_vf, wtmp + 0 * 147456);
  convert_wmp<<<72, 256, 0, stream>>>(w_vr, wtmp + 1 * 147456);
  convert_wmp<<<72, 256, 0, stream>>>(w_hf, wtmp + 2 * 147456);
  convert_wmp<<<72, 256, 0, stream>>>(w_hr, wtmp + 3 * 147456);

  if (use_pad) {
    pad_features<<<19008, 256, 0, stream>>>(features, in_pad);
    conv1_mfma2<<<3600, 256, 0, stream>>>(in_pad, w1t, x1);
  } else {
    conv1_mfma<<<dim3(8, 450), 256, 0, stream>>>(features, w1t, x1);
  }
  stats1<<<512, 256, 0, stream>>>(x1, stats, stats + 1024);
  finalize_bn<<<4, 256, 0, stream>>>(stats, stats + 1024, bn1_s, bn1_b, ab1, 1024, 1.0f/57600.0f);
  bnrelu_x1<<<28800, 256, 0, stream>>>(x1, ab1);
  gemm_mfma_128<<<450, 256, 0, stream>>>(x1, w2t, x2, 1024);
  stats2<<<256, 256, 0, stream>>>(x2, stats + 2048, stats + 2176);
  finalize_bn<<<1, 128, 0, stream>>>(stats + 2048, stats + 2176, bn2_s, bn2_b, ab2, 128, 1.0f/57600.0f);
  apply_bn<<<7200, 256, 0, stream>>>(x2, ab2);

  // fused message passing: 4 launches, weights in VGPRs (256-VGPR cap)
  mp_fused2<7,3><<<NB, 512, 0, stream>>>(x2, wtmp + 0 * 147456, 100, 128,   12800, 0,  +1, 35);
  mp_fused2<7,3><<<NB, 512, 0, stream>>>(x2, wtmp + 1 * 147456, 100, 128,   12800, 35, -1, 35);
  mp_fused2<3,1><<<NB, 512, 0, stream>>>(x2, wtmp + 2 * 147456, 36,  12800, 128,   0,  +1, 99);
  mp_fused2<3,1><<<NB, 512, 0, stream>>>(x2, wtmp + 3 * 147456, 36,  12800, 128,   99, -1, 99);

  seg_head<<<1800, 256, 0, stream>>>(x2, w_seg, b_seg, logits);
  softpool<<<57, 256, 0, stream>>>(logits, pbuf);
  fc1_kernel<<<16, 128, 0, stream>>>(pbuf, w_fc1, b_fc1, zbuf);
  fc2_kernel<<<1, 64, 0, stream>>>(zbuf, w_fc2, b_fc2, outf + 18432000);
  resize_bilinear<<<72000, 256, 0, stream>>>(logits, outf);
}